// Round 15
// baseline (526.353 us; speedup 1.0000x reference)
//
#include <hip/hip_runtime.h>
#include <hip/hip_bf16.h>

typedef __bf16 bf16;
typedef __bf16 bf16x8 __attribute__((ext_vector_type(8)));
typedef __bf16 bf16x4 __attribute__((ext_vector_type(4)));
typedef float  f32x4  __attribute__((ext_vector_type(4)));

// ---------------------------------------------------------------------------
// raw barrier: flush LDS ops (lgkmcnt), DO NOT drain vmcnt — in-flight global
// loads / global_load_lds survive the barrier.
// ---------------------------------------------------------------------------
__device__ __forceinline__ void block_barrier()
{
    asm volatile("s_waitcnt lgkmcnt(0)\n\ts_barrier" ::: "memory");
}

// ---------------------------------------------------------------------------
// async global->LDS 16B per lane: LDS dst = wave-uniform base + lane*16B
// ---------------------------------------------------------------------------
#if defined(__has_builtin)
#if __has_builtin(__builtin_amdgcn_global_load_lds)
#define HAS_GLD 1
#endif
#endif
#ifndef HAS_GLD
#define HAS_GLD 0
#endif

__device__ __forceinline__ void gld_lds16(const bf16* g, bf16* lds_base)
{
#if HAS_GLD
    __builtin_amdgcn_global_load_lds(
        (const __attribute__((address_space(1))) void*)g,
        (__attribute__((address_space(3))) void*)lds_base, 16, 0, 0);
#else
    *(bf16x8*)(lds_base + (threadIdx.x & 63) * 8) = *(const bf16x8*)g;
#endif
}

// ---------------------------------------------------------------------------
// Weight transpose + fp32->bf16: src (K,N) row-major -> dst (N,K)
// ---------------------------------------------------------------------------
__global__ __launch_bounds__(256)
void transpose_cvt(const float* __restrict__ src, bf16* __restrict__ dst, int K, int N)
{
    __shared__ float t[32][33];
    const int bx = blockIdx.x, by = blockIdx.y, tid = threadIdx.x;
    const int c = tid & 31, r0 = tid >> 5;
#pragma unroll
    for (int p = 0; p < 4; p++) {
        int r = r0 + p * 8;
        t[r][c] = src[(size_t)(by * 32 + r) * N + bx * 32 + c];
    }
    __syncthreads();
#pragma unroll
    for (int p = 0; p < 4; p++) {
        int r = r0 + p * 8;
        dst[(size_t)(bx * 32 + r) * K + by * 32 + c] = (bf16)t[c][r];
    }
}

// ---------------------------------------------------------------------------
// plain fp32 -> bf16 convert, 8 elems/thread
// ---------------------------------------------------------------------------
__global__ __launch_bounds__(256)
void cvt_bf16(const float* __restrict__ src, bf16* __restrict__ dst, int n8)
{
    const int i = blockIdx.x * 256 + threadIdx.x;
    if (i >= n8) return;
    const float4* s = (const float4*)(src + (size_t)i * 8);
    float4 a = s[0], b = s[1];
    bf16x8 o;
    o[0] = (bf16)a.x; o[1] = (bf16)a.y; o[2] = (bf16)a.z; o[3] = (bf16)a.w;
    o[4] = (bf16)b.x; o[5] = (bf16)b.y; o[6] = (bf16)b.z; o[7] = (bf16)b.w;
    *(bf16x8*)(dst + (size_t)i * 8) = o;
}

// ---------------------------------------------------------------------------
// Fragment-major repacks: one coalesced 1KB burst per (group, wave) read.
// ---------------------------------------------------------------------------
__global__ __launch_bounds__(256)
void repack_wv(const bf16* __restrict__ Wvt, bf16* __restrict__ Wvf)
{
    const int t = blockIdx.x * 256 + threadIdx.x;
    const int lane = t & 63, g = t >> 6;           // g in [0, 2048)
    const int dt = g & 3, sp = (g >> 2) & 31, h = g >> 7;
    const int lm = lane & 15, q = lane >> 4;
    const bf16x8 v = *(const bf16x8*)(Wvt + (size_t)(h * 64 + dt * 16 + lm) * 1024
                                      + sp * 32 + q * 8);
    *(bf16x8*)(Wvf + (size_t)g * 512 + lane * 8) = v;
}

// Qf[((bt*16 + h)*2 + half)*512 + lane*8] = Qb[(bt*16+lm)*1024 + h*64 + half*32 + q*8]
__global__ __launch_bounds__(256)
void repack_q(const bf16* __restrict__ Qb, bf16* __restrict__ Qf)
{
    const int t = blockIdx.x * 256 + threadIdx.x;  // 1M threads
    const int lane = t & 63, g = t >> 6;           // g in [0, 16384)
    const int half = g & 1, h = (g >> 1) & 15, bt = g >> 5;
    const int lm = lane & 15, q = lane >> 4;
    const bf16x8 v = *(const bf16x8*)(Qb + (size_t)(bt * 16 + lm) * 1024
                                      + h * 64 + half * 32 + q * 8);
    *(bf16x8*)(Qf + (size_t)g * 512 + lane * 8) = v;
}

// Wkf2[(((sp*2+mt)*16+h)*2+half)*512 + lane*8] =
//     Wkb[(sp*32+mt*16+lm)*1024 + h*64 + half*32 + q*8]   (32-i superstep frags)
__global__ __launch_bounds__(256)
void repack_wk2(const bf16* __restrict__ Wkb, bf16* __restrict__ Wkf)
{
    const int t = blockIdx.x * 256 + threadIdx.x;  // 131072 threads
    const int lane = t & 63, g = t >> 6;           // g in [0, 2048)
    const int half = g & 1, h = (g >> 1) & 15, mt = (g >> 5) & 1, sp = g >> 6;
    const int lm = lane & 15, q = lane >> 4;
    const bf16x8 v = *(const bf16x8*)(Wkb + (size_t)(sp * 32 + mt * 16 + lm) * 1024
                                      + h * 64 + half * 32 + q * 8);
    *(bf16x8*)(Wkf + (size_t)g * 512 + lane * 8) = v;
}

// ---------------------------------------------------------------------------
// m97-style GEMM: C = A @ B.  A bf16 (rows via ldA), Bt bf16 (N x K, ldB).
// 128x128 tile, BK=32, global_load_lds staging, XCD swizzle (gridDim.x==8).
// Optional A2 for concat-K (gate).
// ---------------------------------------------------------------------------
template<bool TWOA>
__global__ __launch_bounds__(256)
void gemm_a97(const bf16* __restrict__ A1, const bf16* __restrict__ A2,
              const bf16* __restrict__ Bt, float* __restrict__ Cf,
              bf16* __restrict__ Cb, int Kloop, int Ksplit,
              int ldA, int ldA2, int ldB, int ldC,
              long az, long bz, long cz)
{
    __shared__ bf16 Al[128 * 32];
    __shared__ bf16 Bl[128 * 32];

    const int z = blockIdx.z;
    A1 += (size_t)z * az;
    Bt += (size_t)z * bz;
    if (Cf) Cf += (size_t)z * cz;
    if (Cb) Cb += (size_t)z * cz;

    int bx, by;
    {
        const int gy = gridDim.y;
        const int flat = blockIdx.y * gridDim.x + blockIdx.x;
        if ((gy & 7) == 0 && gridDim.x == 8) {
            const int xcd = flat & 7, slot = flat >> 3, mpx = gy >> 3;
            by = xcd * mpx + (slot >> 3);
            bx = slot & 7;
        } else { bx = blockIdx.x; by = blockIdx.y; }
    }

    const int tid = threadIdx.x;
    const int wave = tid >> 6, lane = tid & 63;
    const int m0 = by * 128, n0 = bx * 128;
    const int rl = lane >> 2;
    const int kc = (lane & 3) * 8;
    const int wm = wave >> 1, wn = wave & 1, lm = lane & 15, quad = lane >> 4;

    f32x4 acc[4][4];
#pragma unroll
    for (int i = 0; i < 4; i++)
#pragma unroll
        for (int j = 0; j < 4; j++)
#pragma unroll
            for (int r = 0; r < 4; r++) acc[i][j][r] = 0.f;

    for (int k0 = 0; k0 < Kloop; k0 += 32) {
        const bf16* Ab; int kof, ld;
        if (TWOA && k0 >= Ksplit) { Ab = A2; kof = k0 - Ksplit; ld = ldA2; }
        else                      { Ab = A1; kof = k0;          ld = ldA;  }
        const int r0 = wave * 32 + rl, r1 = r0 + 16;
        gld_lds16(Ab + (size_t)(m0 + r0) * ld + kof + kc, Al + (wave * 32) * 32);
        gld_lds16(Ab + (size_t)(m0 + r1) * ld + kof + kc, Al + (wave * 32 + 16) * 32);
        gld_lds16(Bt + (size_t)(n0 + r0) * ldB + k0 + kc, Bl + (wave * 32) * 32);
        gld_lds16(Bt + (size_t)(n0 + r1) * ldB + k0 + kc, Bl + (wave * 32 + 16) * 32);
        __syncthreads();

        bf16x8 af[4], bfr[4];
#pragma unroll
        for (int i = 0; i < 4; i++)
            af[i] = *(const bf16x8*)&Al[(wm * 64 + i * 16 + lm) * 32 + quad * 8];
#pragma unroll
        for (int j = 0; j < 4; j++)
            bfr[j] = *(const bf16x8*)&Bl[(wn * 64 + j * 16 + lm) * 32 + quad * 8];
#pragma unroll
        for (int i = 0; i < 4; i++)
#pragma unroll
            for (int j = 0; j < 4; j++)
                acc[i][j] = __builtin_amdgcn_mfma_f32_16x16x32_bf16(af[i], bfr[j], acc[i][j], 0, 0, 0);
        __syncthreads();
    }

#pragma unroll
    for (int i = 0; i < 4; i++) {
        const int rbase = m0 + wm * 64 + i * 16 + quad * 4;
#pragma unroll
        for (int j = 0; j < 4; j++) {
            const int c = n0 + wn * 64 + j * 16 + lm;
#pragma unroll
            for (int r = 0; r < 4; r++) {
                const float v = acc[i][j][r];
                const size_t idx = (size_t)(rbase + r) * ldC + c;
                if (Cf) Cf[idx] = v;
                if (Cb) Cb[idx] = (bf16)v;
            }
        }
    }
}

// ---------------------------------------------------------------------------
// Fused score kernel v4: register double-buffered Wk frags (full-superstep
// cover) + single vmcnt(10) per superstep.
// ---------------------------------------------------------------------------
__global__ __launch_bounds__(512, 4)
void score_attn(const bf16* __restrict__ Qf, const bf16* __restrict__ Wkf,
                const float* __restrict__ mk, float* __restrict__ attn)
{
    __shared__ bf16  Ul[16 * 16 * 32]; // 16KB [b][h][32i] swz ^(((b^h)&7)<<4)
    __shared__ float Ml[2][4096];      // 2x16KB [16b][8 g4][8 k][4 i]

    const int tid  = threadIdx.x;
    const int wave = tid >> 6, lane = tid & 63;
    const int lm = lane & 15, q = lane >> 4;
    const int bt = blockIdx.x;         // rows [bt*16, bt*16+16)
    const int h0 = wave * 2;

    const int gk = lane & 7, gg4 = lane >> 3;

    // ---- persistent Q B-frags (coalesced 1KB bursts, loaded once)
    bf16x8 qf[2][2];
#pragma unroll
    for (int hh = 0; hh < 2; hh++)
#pragma unroll
        for (int half = 0; half < 2; half++)
            qf[hh][half] = *(const bf16x8*)(Qf +
                (size_t)((bt * 16 + h0 + hh) * 2 + half) * 512 + lane * 8);

    f32x4 sacc[2];
#pragma unroll
    for (int lb = 0; lb < 2; lb++)
#pragma unroll
        for (int r = 0; r < 4; r++) sacc[lb][r] = 0.f;

    bf16x8 wkA[2][2][2], wkB[2][2][2];

    // ---- prologue: wkA = wk(0) (8 bursts), DMA(0) -> Ml[0]
#pragma unroll
    for (int hh = 0; hh < 2; hh++)
#pragma unroll
        for (int mt = 0; mt < 2; mt++)
#pragma unroll
            for (int half = 0; half < 2; half++)
                wkA[hh][mt][half] = *(const bf16x8*)(Wkf +
                    (size_t)(((0 * 2 + mt) * 16 + h0 + hh) * 2 + half) * 512 + lane * 8);
#pragma unroll
    for (int m = 0; m < 2; m++) {
        const int row = 2 * wave + m;
        gld_lds16((const bf16*)(mk + (size_t)(bt * 16 + row) * 8192 + gk * 1024 + gg4 * 4),
                  (bf16*)&Ml[0][row * 256]);
    }

#define SCORE_STEP(SP, CUR, NXT) do {                                         \
    const int nspf = ((SP) + 1 < 32) ? (SP) + 1 : 0;                          \
    const int ni_  = nspf * 32;                                               \
    const int nb_  = ((SP) + 1) & 1, cb_ = (SP) & 1;                          \
    /* 1. issue NXT wk(nspf): 8 coalesced 1KB bursts */                       \
    _Pragma("unroll")                                                         \
    for (int hh = 0; hh < 2; hh++)                                            \
        _Pragma("unroll")                                                     \
        for (int mt = 0; mt < 2; mt++)                                        \
            _Pragma("unroll")                                                 \
            for (int half = 0; half < 2; half++)                              \
                NXT[hh][mt][half] = *(const bf16x8*)(Wkf +                    \
                    (size_t)(((nspf * 2 + mt) * 16 + h0 + hh) * 2 + half) * 512 + lane * 8); \
    __builtin_amdgcn_sched_barrier(0);                                        \
    /* 2. DMA slice SP+1 -> Ml[nb_] (own rows) */                             \
    _Pragma("unroll")                                                         \
    for (int m = 0; m < 2; m++) {                                             \
        const int row = 2 * wave + m;                                         \
        gld_lds16((const bf16*)(mk + (size_t)(bt * 16 + row) * 8192 + gk * 1024 + ni_ + gg4 * 4), \
                  (bf16*)&Ml[nb_][row * 256]);                                \
    }                                                                         \
    __builtin_amdgcn_sched_barrier(0);                                        \
    /* 3. one wait: everything older than the 10 just issued is done */       \
    asm volatile("s_waitcnt vmcnt(10)" ::: "memory");                         \
    __builtin_amdgcn_sched_barrier(0);                                        \
    /* 4. U-gen from CUR -> Ul */                                             \
    _Pragma("unroll")                                                         \
    for (int hh = 0; hh < 2; hh++) {                                          \
        const int h = h0 + hh;                                                \
        _Pragma("unroll")                                                     \
        for (int mt = 0; mt < 2; mt++) {                                      \
            f32x4 c4; c4[0] = 0.f; c4[1] = 0.f; c4[2] = 0.f; c4[3] = 0.f;     \
            c4 = __builtin_amdgcn_mfma_f32_16x16x32_bf16(CUR[hh][mt][0], qf[hh][0], c4, 0, 0, 0); \
            c4 = __builtin_amdgcn_mfma_f32_16x16x32_bf16(CUR[hh][mt][1], qf[hh][1], c4, 0, 0, 0); \
            bf16x4 o;                                                         \
            o[0] = (bf16)c4[0]; o[1] = (bf16)c4[1]; o[2] = (bf16)c4[2]; o[3] = (bf16)c4[3]; \
            *(bf16x4*)((char*)Ul + ((((lm * 16 + h) * 32 + mt * 16 + q * 4) * 2) \
                                    ^ (((lm ^ h) & 7) << 4))) = o;            \
        }                                                                     \
    }                                                                         \
    block_barrier();   /* Ul visible; vmem stays in flight */                 \
    /* 5. score accumulate from Ml[cb_] (own rows) */                         \
    _Pragma("unroll")                                                         \
    for (int lb = 0; lb < 2; lb++) {                                          \
        const int bb = wave * 2 + lb;                                         \
        const bf16x8 ua = *(const bf16x8*)((char*)Ul +                        \
            ((((bb * 16 + lm) * 32 + q * 8) * 2) ^ (((bb ^ lm) & 7) << 4)));  \
        const int kk = lm & 7;                                                \
        const f32x4 a0 = *(const f32x4*)&Ml[cb_][bb * 256 + (q * 2) * 32 + kk * 4]; \
        const f32x4 a1 = *(const f32x4*)&Ml[cb_][bb * 256 + (q * 2 + 1) * 32 + kk * 4]; \
        bf16x8 mb;                                                            \
        mb[0] = (bf16)a0[0]; mb[1] = (bf16)a0[1]; mb[2] = (bf16)a0[2]; mb[3] = (bf16)a0[3]; \
        mb[4] = (bf16)a1[0]; mb[5] = (bf16)a1[1]; mb[6] = (bf16)a1[2]; mb[7] = (bf16)a1[3]; \
        sacc[lb] = __builtin_amdgcn_mfma_f32_16x16x32_bf16(ua, mb, sacc[lb], 0, 0, 0); \
    }                                                                         \
    block_barrier();   /* Ul + Ml[cb_] consumed */                            \
} while (0)

    for (int t = 0; t < 16; ++t) {
        SCORE_STEP(2 * t,     wkA, wkB);
        SCORE_STEP(2 * t + 1, wkB, wkA);
    }
#undef SCORE_STEP

    // ---- softmax over k (cols duplicated across lm and lm+8) + store attn
#pragma unroll
    for (int lb = 0; lb < 2; lb++) {
        const size_t bb = (size_t)(bt * 16 + wave * 2 + lb);
#pragma unroll
        for (int r = 0; r < 4; r++) {
            float s = sacc[lb][r] * 0.125f;          // DH^-0.5
            float mx = s;
            mx = fmaxf(mx, __shfl_xor(mx, 1));
            mx = fmaxf(mx, __shfl_xor(mx, 2));
            mx = fmaxf(mx, __shfl_xor(mx, 4));
            mx = fmaxf(mx, __shfl_xor(mx, 8));
            const float e = __expf(s - mx);
            float d = e;
            d += __shfl_xor(d, 1);
            d += __shfl_xor(d, 2);
            d += __shfl_xor(d, 4);
            d += __shfl_xor(d, 8);                   // = 2 * true denom
            const float a = e * (2.f / d);
            if (lm < 8) attn[bb * 128 + (q * 4 + r) * 8 + lm] = a;
        }
    }
}

// ---------------------------------------------------------------------------
// Fused apply kernel v11: register double-buffered Wvf frags + single
// vmcnt(10) per superstep; 2-buffer Vl32 DMA (1 ahead, full-superstep cover).
// ---------------------------------------------------------------------------
__global__ __launch_bounds__(512, 4)
void apply_attn(const float* __restrict__ attn, const float* __restrict__ mv,
                const bf16* __restrict__ Wvf, bf16* __restrict__ OH)
{
    __shared__ float Vl32[2][4096];    // 2x16KB [16 rows][8 k][32 i] fp32, LINEAR
    __shared__ bf16  Wl[16 * 16 * 32]; // 16KB [b][h][32 i] swz ^(((b^h)&7)<<4)

    const int tid  = threadIdx.x;
    const int wave = tid >> 6, lane = tid & 63;
    const int lm = lane & 15, q = lane >> 4;
    const int b0 = blockIdx.x * 16;
    const int h0 = wave * 2;

    const int gk = lane >> 3, gi4 = (lane & 7) * 4;

    // ---- attn B-frag variants: afv[lb][mt] nonzero only where q==mt (mt 0..1)
    bf16x8 afv[2][2];
#pragma unroll
    for (int lb = 0; lb < 2; lb++) {
        const float* ap = attn + (size_t)(b0 + wave * 2 + lb) * 128 + lm * 8;
        const float4 x = *(const float4*)(ap);
        const float4 y = *(const float4*)(ap + 4);
        bf16 a8[8];
        a8[0] = (bf16)x.x; a8[1] = (bf16)x.y; a8[2] = (bf16)x.z; a8[3] = (bf16)x.w;
        a8[4] = (bf16)y.x; a8[5] = (bf16)y.y; a8[6] = (bf16)y.z; a8[7] = (bf16)y.w;
#pragma unroll
        for (int mt = 0; mt < 2; mt++) {
            bf16x8 t;
#pragma unroll
            for (int j = 0; j < 8; j++) t[j] = (q == mt) ? a8[j] : (bf16)0.f;
            afv[lb][mt] = t;
        }
    }

    f32x4 oacc[2][4];
#pragma unroll
    for (int i = 0; i < 2; i++)
#pragma unroll
        for (int j = 0; j < 4; j++)
#pragma unroll
            for (int r = 0; r < 4; r++) oacc[i][j][r] = 0.f;

    bf16x8 wbA[2][4], wbB[2][4];

    // ---- prologue: wbA = wb(0) (8 bursts), DMA(0) -> Vl32[0]
#pragma unroll
    for (int hh = 0; hh < 2; hh++) {
        const int h = h0 + hh;
#pragma unroll
        for (int dt = 0; dt < 4; dt++)
            wbA[hh][dt] = *(const bf16x8*)(Wvf +
                ((((size_t)h * 32 + 0) * 4 + dt) * 512 + lane * 8));
    }
#pragma unroll
    for (int m = 0; m < 2; m++) {
        const int row = 2 * wave + m;
        gld_lds16((const bf16*)(mv + (size_t)(b0 + row) * 8192 + gk * 1024 + gi4),
                  (bf16*)&Vl32[0][row * 256]);
    }

#define APPLY_STEP(SP, CUR, NXT) do {                                         \
    const int nspf = ((SP) + 1 < 32) ? (SP) + 1 : 0;                          \
    const int ni_  = nspf * 32;                                               \
    const int nb_  = ((SP) + 1) & 1, cb_ = (SP) & 1;                          \
    /* 1. issue NXT wb(nspf): 8 coalesced 1KB bursts */                       \
    _Pragma("unroll")                                                         \
    for (int hh = 0; hh < 2; hh++) {                                          \
        const int h = h0 + hh;                                                \
        _Pragma("unroll")                                                     \
        for (int dt = 0; dt < 4; dt++)                                        \
            NXT[hh][dt] = *(const bf16x8*)(Wvf +                              \
                ((((size_t)h * 32 + nspf) * 4 + dt) * 512 + lane * 8));       \
    }                                                                         \
    __builtin_amdgcn_sched_barrier(0);                                        \
    /* 2. DMA mv slice SP+1 -> Vl32[nb_] (own rows) */                        \
    _Pragma("unroll")                                                         \
    for (int m = 0; m < 2; m++) {                                             \
        const int row = 2 * wave + m;                                         \
        gld_lds16((const bf16*)(mv + (size_t)(b0 + row) * 8192 + gk * 1024 + ni_ + gi4), \
                  (bf16*)&Vl32[nb_][row * 256]);                              \
    }                                                                         \
    __builtin_amdgcn_sched_barrier(0);                                        \
    /* 3. one wait: wb(SP) + DMA(SP) landed (full superstep of cover) */      \
    asm volatile("s_waitcnt vmcnt(10)" ::: "memory");                         \
    __builtin_amdgcn_sched_barrier(0);                                        \
    /* 4. Wm-gen from Vl32[cb_] (own rows) -> Wl */                           \
    _Pragma("unroll")                                                         \
    for (int lb = 0; lb < 2; lb++) {                                          \
        const int row = 2 * wave + lb;                                        \
        const int il = (q & 1) * 16 + lm;                                     \
        float v[8];                                                           \
        _Pragma("unroll")                                                     \
        for (int k = 0; k < 8; k++) v[k] = Vl32[cb_][row * 256 + k * 32 + il]; \
        bf16x8 avf;                                                           \
        _Pragma("unroll")                                                     \
        for (int k = 0; k < 8; k++) avf[k] = (bf16)v[k];                      \
        _Pragma("unroll")                                                     \
        for (int mt = 0; mt < 2; mt++) {                                      \
            f32x4 c; c[0] = 0.f; c[1] = 0.f; c[2] = 0.f; c[3] = 0.f;          \
            c = __builtin_amdgcn_mfma_f32_16x16x32_bf16(avf, afv[lb][mt], c, 0, 0, 0); \
            bf16x4 o;                                                         \
            o[0] = (bf16)c[0]; o[1] = (bf16)c[1]; o[2] = (bf16)c[2]; o[3] = (bf16)c[3]; \
            *(bf16x4*)((char*)Wl + ((((row * 16 + lm) * 32 + mt * 16 + q * 4) * 2) \
                                    ^ (((row ^ lm) & 7) << 4))) = o;          \
        }                                                                     \
    }                                                                         \
    block_barrier();   /* Wl visible; vmem stays in flight */                 \
    /* 5. OH: Wl reads + CUR wb regs */                                       \
    _Pragma("unroll")                                                         \
    for (int hh = 0; hh < 2; hh++) {                                          \
        const int h = h0 + hh;                                                \
        const bf16x8 wa = *(const bf16x8*)((char*)Wl +                        \
            ((((lm * 16 + h) * 32 + q * 8) * 2) ^ (((lm ^ h) & 7) << 4)));    \
        _Pragma("unroll")                                                     \
        for (int dt = 0; dt < 4; dt++)                                        \
            oacc[hh][dt] = __builtin_amdgcn_mfma_f32_16x16x32_bf16(wa, CUR[hh][dt], oacc[hh][dt], 0, 0, 0); \
    }                                                                         \
    block_barrier();   /* Wl consumed */                                      \
} while (0)

    for (int t = 0; t < 16; ++t) {
        APPLY_STEP(2 * t,     wbA, wbB);
        APPLY_STEP(2 * t + 1, wbB, wbA);
    }
#undef APPLY_STEP

    // ---- store OH (rows b = q*4+r, cols h*64 + dt*16 + lm)
#pragma unroll
    for (int hh = 0; hh < 2; hh++) {
        const int h = h0 + hh;
#pragma unroll
        for (int dt = 0; dt < 4; dt++) {
#pragma unroll
            for (int r = 0; r < 4; r++)
                OH[(size_t)(b0 + q * 4 + r) * 1024 + h * 64 + dt * 16 + lm] = (bf16)oacc[hh][dt][r];
        }
    }
}

// ---------------------------------------------------------------------------
// sigmoid gate + residual + LayerNorm. One block per row.
// ---------------------------------------------------------------------------
__global__ __launch_bounds__(256)
void gate_ln_kernel(const float* __restrict__ hs, const float* __restrict__ mo,
                    const float* __restrict__ z,  const float* __restrict__ bg,
                    const float* __restrict__ lng, const float* __restrict__ lnb,
                    float* __restrict__ out)
{
    __shared__ float s1[4], s2[4];
    const int tid = threadIdx.x;
    const size_t base = (size_t)blockIdx.x * 1024 + tid * 4;

    const float4 h4 = *(const float4*)&hs[base];
    const float4 m4 = *(const float4*)&mo[base];
    const float4 z4 = *(const float4*)&z[base];
    const float4 bg4 = *(const float4*)&bg[tid * 4];

    float a[4];
    {
        const float g0 = 1.f / (1.f + __expf(-(z4.x + bg4.x)));
        const float g1 = 1.f / (1.f + __expf(-(z4.y + bg4.y)));
        const float g2 = 1.f / (1.f + __expf(-(z4.z + bg4.z)));
        const float g3 = 1.f / (1.f + __expf(-(z4.w + bg4.w)));
        a[0] = h4.x + g0 * m4.x;
        a[1] = h4.y + g1 * m4.y;
        a[2] = h4.z + g2 * m4.z;
        a[3] = h4.w + g3 * m4.w;
    }
    float sum = a[0] + a[1] + a[2] + a[3];
    float sq  = a[0]*a[0] + a[1]*a[1] + a[2]*a[2] + a[3]*a[3];
#pragma unroll
    for (int off = 32; off >= 1; off >>= 1) {
        sum += __shfl_xor(sum, off);
        sq  += __shfl_xor(sq,  off);
    }
    const int wave = tid >> 6;
    if ((tid & 63) == 0) { s1[wave] = sum; s2[wave] = sq; }
    __syncthreads();
    const float mean = (s1[0] + s1[1] + s1[2] + s1[3]) * (1.f / 1024.f);
    const float var  = (s2[0] + s2[1] + s2[2] + s2[3]) * (1.f / 1024.f) - mean * mean;
    const float inv  = rsqrtf(var + 1e-5f);

    const float4 g4 = *(const float4*)&lng[tid * 4];
    const float4 b4 = *(const float4*)&lnb[tid * 4];
    float4 o;
    o.x = (a[0] - mean) * inv * g4.x + b4.x;
    o.y = (a[1] - mean) * inv * g4.y + b4.y;
    o.z = (a[2] - mean) * inv * g4.z + b4.z;
    o.w = (a[3] - mean) * inv * g4.w + b4.w;
    *(float4*)&out[base] = o;
}

// ---------------------------------------------------------------------------
extern "C" void kernel_launch(void* const* d_in, const int* in_sizes, int n_in,
                              void* d_out, int out_size, void* d_ws, size_t ws_size,
                              hipStream_t stream)
{
    const float* hs  = (const float*)d_in[0];
    const float* mk  = (const float*)d_in[1];
    const float* mv  = (const float*)d_in[2];
    const float* Wq  = (const float*)d_in[3];
    const float* Wk  = (const float*)d_in[4];
    const float* Wv  = (const float*)d_in[5];
    const float* Wo  = (const float*)d_in[6];
    const float* Wg  = (const float*)d_in[7];
    const float* bg  = (const float*)d_in[8];
    const float* lng = (const float*)d_in[9];
    const float* lnb = (const float*)d_in[10];
    float* out = (float*)d_out;

    const int B = 8192;
    const dim3 tb(256);

    char* ws = (char*)d_ws;
    bf16*  Wq_t = (bf16*)(ws);                        // 2 MB  (1024x1024, N x K)
    bf16*  Wv_t = (bf16*)(ws + ((size_t)2  << 20));   // 2 MB
    bf16*  Wo_t = (bf16*)(ws + ((size_t)4  << 20));   // 2 MB
    bf16*  Wg_t = (bf16*)(ws + ((size_t)6  << 20));   // 4 MB  (1024x2048)
    bf16*  Wk_b = (bf16*)(ws + ((size_t)10 << 20));   // 2 MB  (1024x1024, NOT transposed)
    bf16*  hs_b = (bf16*)(ws + ((size_t)12 << 20));   // 16 MB (8192x1024)
    bf16*  Qb   = (bf16*)(ws + ((size_t)28 << 20));   // 16 MB
    bf16*  OH   = (bf16*)(ws + ((size_t)44 << 20));   // 16 MB
    float* Mo   = (float*)(ws + ((size_t)60 << 20));  // 32 MB
    bf16*  Mo_b = (bf16*)(ws + ((size_t)92 << 20));   // 16 MB
    float* Zb   = (float*)(ws + ((size_t)108 << 20)); // 32 MB
    float* At   = (float*)(ws + ((size_t)140 << 20)); // 4 MB  (8192x16x8 fp32)
    bf16*  Wvf  = (bf16*)(ws + ((size_t)208 << 20));  // 2 MB  (fragment-major Wv)
    bf16*  Wkf  = (bf16*)(ws + ((size_t)210 << 20));  // 2 MB  (fragment-major Wk, 32-i)
    bf16*  Qf   = (bf16*)(ws + ((size_t)212 << 20));  // 16 MB (fragment-major Q)

    transpose_cvt<<<dim3(32, 32), tb, 0, stream>>>(Wq, Wq_t, 1024, 1024);
    transpose_cvt<<<dim3(32, 32), tb, 0, stream>>>(Wv, Wv_t, 1024, 1024);
    transpose_cvt<<<dim3(32, 32), tb, 0, stream>>>(Wo, Wo_t, 1024, 1024);
    transpose_cvt<<<dim3(32, 64), tb, 0, stream>>>(Wg, Wg_t, 2048, 1024);
    cvt_bf16<<<dim3(1024 * 1024 / 8 / 256), tb, 0, stream>>>(Wk, Wk_b, 1024 * 1024 / 8);
    cvt_bf16<<<dim3(B * 1024 / 8 / 256), tb, 0, stream>>>(hs, hs_b, B * 1024 / 8);
    repack_wv<<<dim3(512), tb, 0, stream>>>(Wv_t, Wvf);
    repack_wk2<<<dim3(512), tb, 0, stream>>>(Wk_b, Wkf);

    // Q = hs @ Wq -> bf16 (B x 1024)
    gemm_a97<false><<<dim3(8, 64, 1), tb, 0, stream>>>(
        hs_b, nullptr, Wq_t, nullptr, Qb,
        1024, 1024, 1024, 0, 1024, 1024, 0, 0, 0);
    // fragment-major Q for the score kernel
    repack_q<<<dim3(4096), tb, 0, stream>>>(Qb, Qf);
    // fused: U-gen + scores + softmax -> attn (B x 16 x 8 fp32)
    score_attn<<<dim3(B / 16), dim3(512), 0, stream>>>(Qf, Wkf, mk, At);
    // fused: W_mix-gen + V-proj -> OH (B x 1024 bf16)
    apply_attn<<<dim3(B / 16), dim3(512), 0, stream>>>(At, mv, Wvf, OH);
    // memory_out = OH @ Wo -> fp32 Mo + bf16 Mo_b
    gemm_a97<false><<<dim3(8, 64, 1), tb, 0, stream>>>(
        OH, nullptr, Wo_t, Mo, Mo_b,
        1024, 1024, 1024, 0, 1024, 1024, 0, 0, 0);
    // z = [hs, Mo] @ Wg -> fp32
    gemm_a97<true><<<dim3(8, 64, 1), tb, 0, stream>>>(
        hs_b, Mo_b, Wg_t, Zb, nullptr,
        2048, 1024, 1024, 1024, 2048, 1024, 0, 0, 0);
    // gate + residual + LayerNorm
    gate_ln_kernel<<<dim3(B), tb, 0, stream>>>(
        hs, Mo, Zb, bg, lng, lnb, out);
}

// Round 16
// 406.405 us; speedup vs baseline: 1.2951x; 1.2951x over previous
//
#include <hip/hip_runtime.h>
#include <hip/hip_bf16.h>

typedef __bf16 bf16;
typedef __bf16 bf16x8 __attribute__((ext_vector_type(8)));
typedef __bf16 bf16x4 __attribute__((ext_vector_type(4)));
typedef float  f32x4  __attribute__((ext_vector_type(4)));

// ---------------------------------------------------------------------------
// raw barrier: flush LDS ops (lgkmcnt), DO NOT drain vmcnt — in-flight global
// loads / global_load_lds survive the barrier.
// ---------------------------------------------------------------------------
__device__ __forceinline__ void block_barrier()
{
    asm volatile("s_waitcnt lgkmcnt(0)\n\ts_barrier" ::: "memory");
}

// ---------------------------------------------------------------------------
// async global->LDS 16B per lane: LDS dst = wave-uniform base + lane*16B
// ---------------------------------------------------------------------------
#if defined(__has_builtin)
#if __has_builtin(__builtin_amdgcn_global_load_lds)
#define HAS_GLD 1
#endif
#endif
#ifndef HAS_GLD
#define HAS_GLD 0
#endif

__device__ __forceinline__ void gld_lds16(const bf16* g, bf16* lds_base)
{
#if HAS_GLD
    __builtin_amdgcn_global_load_lds(
        (const __attribute__((address_space(1))) void*)g,
        (__attribute__((address_space(3))) void*)lds_base, 16, 0, 0);
#else
    *(bf16x8*)(lds_base + (threadIdx.x & 63) * 8) = *(const bf16x8*)g;
#endif
}

// ---------------------------------------------------------------------------
// Weight transpose + fp32->bf16: src (K,N) row-major -> dst (N,K)
// ---------------------------------------------------------------------------
__global__ __launch_bounds__(256)
void transpose_cvt(const float* __restrict__ src, bf16* __restrict__ dst, int K, int N)
{
    __shared__ float t[32][33];
    const int bx = blockIdx.x, by = blockIdx.y, tid = threadIdx.x;
    const int c = tid & 31, r0 = tid >> 5;
#pragma unroll
    for (int p = 0; p < 4; p++) {
        int r = r0 + p * 8;
        t[r][c] = src[(size_t)(by * 32 + r) * N + bx * 32 + c];
    }
    __syncthreads();
#pragma unroll
    for (int p = 0; p < 4; p++) {
        int r = r0 + p * 8;
        dst[(size_t)(bx * 32 + r) * K + by * 32 + c] = (bf16)t[c][r];
    }
}

// ---------------------------------------------------------------------------
// plain fp32 -> bf16 convert, 8 elems/thread
// ---------------------------------------------------------------------------
__global__ __launch_bounds__(256)
void cvt_bf16(const float* __restrict__ src, bf16* __restrict__ dst, int n8)
{
    const int i = blockIdx.x * 256 + threadIdx.x;
    if (i >= n8) return;
    const float4* s = (const float4*)(src + (size_t)i * 8);
    float4 a = s[0], b = s[1];
    bf16x8 o;
    o[0] = (bf16)a.x; o[1] = (bf16)a.y; o[2] = (bf16)a.z; o[3] = (bf16)a.w;
    o[4] = (bf16)b.x; o[5] = (bf16)b.y; o[6] = (bf16)b.z; o[7] = (bf16)b.w;
    *(bf16x8*)(dst + (size_t)i * 8) = o;
}

// ---------------------------------------------------------------------------
// Fragment-major repacks: one coalesced 1KB burst per (group, wave) read.
// ---------------------------------------------------------------------------
__global__ __launch_bounds__(256)
void repack_wv(const bf16* __restrict__ Wvt, bf16* __restrict__ Wvf)
{
    const int t = blockIdx.x * 256 + threadIdx.x;
    const int lane = t & 63, g = t >> 6;           // g in [0, 2048)
    const int dt = g & 3, sp = (g >> 2) & 31, h = g >> 7;
    const int lm = lane & 15, q = lane >> 4;
    const bf16x8 v = *(const bf16x8*)(Wvt + (size_t)(h * 64 + dt * 16 + lm) * 1024
                                      + sp * 32 + q * 8);
    *(bf16x8*)(Wvf + (size_t)g * 512 + lane * 8) = v;
}

// Qf[((bt*16 + h)*2 + half)*512 + lane*8] = Qb[(bt*16+lm)*1024 + h*64 + half*32 + q*8]
__global__ __launch_bounds__(256)
void repack_q(const bf16* __restrict__ Qb, bf16* __restrict__ Qf)
{
    const int t = blockIdx.x * 256 + threadIdx.x;  // 1M threads
    const int lane = t & 63, g = t >> 6;           // g in [0, 16384)
    const int half = g & 1, h = (g >> 1) & 15, bt = g >> 5;
    const int lm = lane & 15, q = lane >> 4;
    const bf16x8 v = *(const bf16x8*)(Qb + (size_t)(bt * 16 + lm) * 1024
                                      + h * 64 + half * 32 + q * 8);
    *(bf16x8*)(Qf + (size_t)g * 512 + lane * 8) = v;
}

// Wkf2[(((sp*2+mt)*16+h)*2+half)*512 + lane*8] =
//     Wkb[(sp*32+mt*16+lm)*1024 + h*64 + half*32 + q*8]   (32-i superstep frags)
__global__ __launch_bounds__(256)
void repack_wk2(const bf16* __restrict__ Wkb, bf16* __restrict__ Wkf)
{
    const int t = blockIdx.x * 256 + threadIdx.x;  // 131072 threads
    const int lane = t & 63, g = t >> 6;           // g in [0, 2048)
    const int half = g & 1, h = (g >> 1) & 15, mt = (g >> 5) & 1, sp = g >> 6;
    const int lm = lane & 15, q = lane >> 4;
    const bf16x8 v = *(const bf16x8*)(Wkb + (size_t)(sp * 32 + mt * 16 + lm) * 1024
                                      + h * 64 + half * 32 + q * 8);
    *(bf16x8*)(Wkf + (size_t)g * 512 + lane * 8) = v;
}

// ---------------------------------------------------------------------------
// m97-style GEMM: C = A @ B.  A bf16 (rows via ldA), Bt bf16 (N x K, ldB).
// 128x128 tile, BK=32, global_load_lds staging, XCD swizzle (gridDim.x==8).
// Optional A2 for concat-K (gate).
// ---------------------------------------------------------------------------
template<bool TWOA>
__global__ __launch_bounds__(256)
void gemm_a97(const bf16* __restrict__ A1, const bf16* __restrict__ A2,
              const bf16* __restrict__ Bt, float* __restrict__ Cf,
              bf16* __restrict__ Cb, int Kloop, int Ksplit,
              int ldA, int ldA2, int ldB, int ldC,
              long az, long bz, long cz)
{
    __shared__ bf16 Al[128 * 32];
    __shared__ bf16 Bl[128 * 32];

    const int z = blockIdx.z;
    A1 += (size_t)z * az;
    Bt += (size_t)z * bz;
    if (Cf) Cf += (size_t)z * cz;
    if (Cb) Cb += (size_t)z * cz;

    int bx, by;
    {
        const int gy = gridDim.y;
        const int flat = blockIdx.y * gridDim.x + blockIdx.x;
        if ((gy & 7) == 0 && gridDim.x == 8) {
            const int xcd = flat & 7, slot = flat >> 3, mpx = gy >> 3;
            by = xcd * mpx + (slot >> 3);
            bx = slot & 7;
        } else { bx = blockIdx.x; by = blockIdx.y; }
    }

    const int tid = threadIdx.x;
    const int wave = tid >> 6, lane = tid & 63;
    const int m0 = by * 128, n0 = bx * 128;
    const int rl = lane >> 2;
    const int kc = (lane & 3) * 8;
    const int wm = wave >> 1, wn = wave & 1, lm = lane & 15, quad = lane >> 4;

    f32x4 acc[4][4];
#pragma unroll
    for (int i = 0; i < 4; i++)
#pragma unroll
        for (int j = 0; j < 4; j++)
#pragma unroll
            for (int r = 0; r < 4; r++) acc[i][j][r] = 0.f;

    for (int k0 = 0; k0 < Kloop; k0 += 32) {
        const bf16* Ab; int kof, ld;
        if (TWOA && k0 >= Ksplit) { Ab = A2; kof = k0 - Ksplit; ld = ldA2; }
        else                      { Ab = A1; kof = k0;          ld = ldA;  }
        const int r0 = wave * 32 + rl, r1 = r0 + 16;
        gld_lds16(Ab + (size_t)(m0 + r0) * ld + kof + kc, Al + (wave * 32) * 32);
        gld_lds16(Ab + (size_t)(m0 + r1) * ld + kof + kc, Al + (wave * 32 + 16) * 32);
        gld_lds16(Bt + (size_t)(n0 + r0) * ldB + k0 + kc, Bl + (wave * 32) * 32);
        gld_lds16(Bt + (size_t)(n0 + r1) * ldB + k0 + kc, Bl + (wave * 32 + 16) * 32);
        __syncthreads();

        bf16x8 af[4], bfr[4];
#pragma unroll
        for (int i = 0; i < 4; i++)
            af[i] = *(const bf16x8*)&Al[(wm * 64 + i * 16 + lm) * 32 + quad * 8];
#pragma unroll
        for (int j = 0; j < 4; j++)
            bfr[j] = *(const bf16x8*)&Bl[(wn * 64 + j * 16 + lm) * 32 + quad * 8];
#pragma unroll
        for (int i = 0; i < 4; i++)
#pragma unroll
            for (int j = 0; j < 4; j++)
                acc[i][j] = __builtin_amdgcn_mfma_f32_16x16x32_bf16(af[i], bfr[j], acc[i][j], 0, 0, 0);
        __syncthreads();
    }

#pragma unroll
    for (int i = 0; i < 4; i++) {
        const int rbase = m0 + wm * 64 + i * 16 + quad * 4;
#pragma unroll
        for (int j = 0; j < 4; j++) {
            const int c = n0 + wn * 64 + j * 16 + lm;
#pragma unroll
            for (int r = 0; r < 4; r++) {
                const float v = acc[i][j][r];
                const size_t idx = (size_t)(rbase + r) * ldC + c;
                if (Cf) Cf[idx] = v;
                if (Cb) Cb[idx] = (bf16)v;
            }
        }
    }
}

// ---------------------------------------------------------------------------
// Fused score kernel v5: R13 structure + register-NEUTRAL wk latency cover.
// Single wk register buffer; wk(sp+1) is issued right AFTER U-gen(sp)
// consumes the regs (pure WAR reuse).  Issue order: DMA(sp) < wk(sp) <
// DMA(sp+1), so the top-of-superstep vmcnt(2) (leaving only DMA(sp+1))
// guarantees wk(sp)+DMA(sp) landed — wk now has [score + 2 barriers +
// DMA issue] of cover instead of zero.  No new registers vs R13.
// ---------------------------------------------------------------------------
__global__ __launch_bounds__(512, 4)
void score_attn(const bf16* __restrict__ Qf, const bf16* __restrict__ Wkf,
                const float* __restrict__ mk, float* __restrict__ attn)
{
    __shared__ bf16  Ul[16 * 16 * 32]; // 16KB [b][h][32i] swz ^(((b^h)&7)<<4)
    __shared__ float Ml[2][4096];      // 2x16KB [16b][8 g4][8 k][4 i]

    const int tid  = threadIdx.x;
    const int wave = tid >> 6, lane = tid & 63;
    const int lm = lane & 15, q = lane >> 4;
    const int bt = blockIdx.x;         // rows [bt*16, bt*16+16)
    const int h0 = wave * 2;

    const int gk = lane & 7, gg4 = lane >> 3;

    // ---- persistent Q B-frags (coalesced 1KB bursts, loaded once)
    bf16x8 qf[2][2];
#pragma unroll
    for (int hh = 0; hh < 2; hh++)
#pragma unroll
        for (int half = 0; half < 2; half++)
            qf[hh][half] = *(const bf16x8*)(Qf +
                (size_t)((bt * 16 + h0 + hh) * 2 + half) * 512 + lane * 8);

    f32x4 sacc[2];
#pragma unroll
    for (int lb = 0; lb < 2; lb++)
#pragma unroll
        for (int r = 0; r < 4; r++) sacc[lb][r] = 0.f;

    // single wk register buffer (8 bf16x8 = 32 VGPR, same as R13)
    bf16x8 wk[2][2][2];

    // ---- prologue: wk(0) (8 bursts), DMA(0) -> Ml[0]
#pragma unroll
    for (int hh = 0; hh < 2; hh++)
#pragma unroll
        for (int mt = 0; mt < 2; mt++)
#pragma unroll
            for (int half = 0; half < 2; half++)
                wk[hh][mt][half] = *(const bf16x8*)(Wkf +
                    (size_t)(((0 * 2 + mt) * 16 + h0 + hh) * 2 + half) * 512 + lane * 8);
#pragma unroll
    for (int m = 0; m < 2; m++) {
        const int row = 2 * wave + m;
        gld_lds16((const bf16*)(mk + (size_t)(bt * 16 + row) * 8192 + gk * 1024 + gg4 * 4),
                  (bf16*)&Ml[0][row * 256]);
    }

    for (int sp = 0; sp < 32; ++sp) {
        const int nspf = (sp + 1 < 32) ? sp + 1 : 0;  // tail wraps (data unused)
        const int ni   = nspf * 32;
        const int nb   = (sp + 1) & 1, cb = sp & 1;

        // ---- 1. DMA slice sp+1 -> Ml[nb] (own rows; youngest vmem)
#pragma unroll
        for (int m = 0; m < 2; m++) {
            const int row = 2 * wave + m;
            gld_lds16((const bf16*)(mk + (size_t)(bt * 16 + row) * 8192 + gk * 1024 + ni + gg4 * 4),
                      (bf16*)&Ml[nb][row * 256]);
        }
        __builtin_amdgcn_sched_barrier(0);

        // ---- 2. wait: only DMA(sp+1) outstanding -> wk(sp)+DMA(sp) landed
        asm volatile("s_waitcnt vmcnt(2)" ::: "memory");
        __builtin_amdgcn_sched_barrier(0);

        // ---- 3. U-gen from wk(sp) -> Ul
#pragma unroll
        for (int hh = 0; hh < 2; hh++) {
            const int h = h0 + hh;
#pragma unroll
            for (int mt = 0; mt < 2; mt++) {
                f32x4 c4;
                c4[0] = 0.f; c4[1] = 0.f; c4[2] = 0.f; c4[3] = 0.f;
                c4 = __builtin_amdgcn_mfma_f32_16x16x32_bf16(wk[hh][mt][0], qf[hh][0], c4, 0, 0, 0);
                c4 = __builtin_amdgcn_mfma_f32_16x16x32_bf16(wk[hh][mt][1], qf[hh][1], c4, 0, 0, 0);
                bf16x4 o;
                o[0] = (bf16)c4[0]; o[1] = (bf16)c4[1]; o[2] = (bf16)c4[2]; o[3] = (bf16)c4[3];
                *(bf16x4*)((char*)Ul + ((((lm * 16 + h) * 32 + mt * 16 + q * 4) * 2)
                                        ^ (((lm ^ h) & 7) << 4))) = o;
            }
        }
        __builtin_amdgcn_sched_barrier(0);

        // ---- 4. issue wk(sp+1) into the SAME regs (WAR after U-gen)
#pragma unroll
        for (int hh = 0; hh < 2; hh++)
#pragma unroll
            for (int mt = 0; mt < 2; mt++)
#pragma unroll
                for (int half = 0; half < 2; half++)
                    wk[hh][mt][half] = *(const bf16x8*)(Wkf +
                        (size_t)(((nspf * 2 + mt) * 16 + h0 + hh) * 2 + half) * 512 + lane * 8);
        __builtin_amdgcn_sched_barrier(0);

        block_barrier();   // Ul visible (lgkm only; vmem stays in flight)

        // ---- 5. score accumulate from Ml[cb] (own rows)
#pragma unroll
        for (int lb = 0; lb < 2; lb++) {
            const int bb = wave * 2 + lb;
            const bf16x8 ua = *(const bf16x8*)((char*)Ul +
                ((((bb * 16 + lm) * 32 + q * 8) * 2) ^ (((bb ^ lm) & 7) << 4)));
            const int kk = lm & 7;
            const f32x4 a0 = *(const f32x4*)&Ml[cb][bb * 256 + (q * 2) * 32 + kk * 4];
            const f32x4 a1 = *(const f32x4*)&Ml[cb][bb * 256 + (q * 2 + 1) * 32 + kk * 4];
            bf16x8 mb;
            mb[0] = (bf16)a0[0]; mb[1] = (bf16)a0[1]; mb[2] = (bf16)a0[2]; mb[3] = (bf16)a0[3];
            mb[4] = (bf16)a1[0]; mb[5] = (bf16)a1[1]; mb[6] = (bf16)a1[2]; mb[7] = (bf16)a1[3];
            sacc[lb] = __builtin_amdgcn_mfma_f32_16x16x32_bf16(ua, mb, sacc[lb], 0, 0, 0);
        }
        block_barrier();   // Ul + Ml[cb] consumed
    }

    // ---- softmax over k (cols duplicated across lm and lm+8) + store attn
#pragma unroll
    for (int lb = 0; lb < 2; lb++) {
        const size_t bb = (size_t)(bt * 16 + wave * 2 + lb);
#pragma unroll
        for (int r = 0; r < 4; r++) {
            float s = sacc[lb][r] * 0.125f;          // DH^-0.5
            float mx = s;
            mx = fmaxf(mx, __shfl_xor(mx, 1));
            mx = fmaxf(mx, __shfl_xor(mx, 2));
            mx = fmaxf(mx, __shfl_xor(mx, 4));
            mx = fmaxf(mx, __shfl_xor(mx, 8));
            const float e = __expf(s - mx);
            float d = e;
            d += __shfl_xor(d, 1);
            d += __shfl_xor(d, 2);
            d += __shfl_xor(d, 4);
            d += __shfl_xor(d, 8);                   // = 2 * true denom
            const float a = e * (2.f / d);
            if (lm < 8) attn[bb * 128 + (q * 4 + r) * 8 + lm] = a;
        }
    }
}

// ---------------------------------------------------------------------------
// Fused apply kernel v10 (verified R11/R13): fragment-major Wvf + 3-buffer
// DMA mv staging, vmcnt(12)/vmcnt(2).  Reverted verbatim.
// ---------------------------------------------------------------------------
__global__ __launch_bounds__(512, 4)
void apply_attn(const float* __restrict__ attn, const float* __restrict__ mv,
                const bf16* __restrict__ Wvf, bf16* __restrict__ OH)
{
    __shared__ float Vl32[3][4096];    // 3x16KB [16 rows][8 k][32 i] fp32, LINEAR
    __shared__ bf16  Wl[16 * 16 * 32]; // 16KB [b][h][32 i] swz ^(((b^h)&7)<<4)

    const int tid  = threadIdx.x;
    const int wave = tid >> 6, lane = tid & 63;
    const int lm = lane & 15, q = lane >> 4;
    const int b0 = blockIdx.x * 16;
    const int h0 = wave * 2;

    const int gk = lane >> 3, gi4 = (lane & 7) * 4;

    bf16x8 afv[2][2];
#pragma unroll
    for (int lb = 0; lb < 2; lb++) {
        const float* ap = attn + (size_t)(b0 + wave * 2 + lb) * 128 + lm * 8;
        const float4 x = *(const float4*)(ap);
        const float4 y = *(const float4*)(ap + 4);
        bf16 a8[8];
        a8[0] = (bf16)x.x; a8[1] = (bf16)x.y; a8[2] = (bf16)x.z; a8[3] = (bf16)x.w;
        a8[4] = (bf16)y.x; a8[5] = (bf16)y.y; a8[6] = (bf16)y.z; a8[7] = (bf16)y.w;
#pragma unroll
        for (int mt = 0; mt < 2; mt++) {
            bf16x8 t;
#pragma unroll
            for (int j = 0; j < 8; j++) t[j] = (q == mt) ? a8[j] : (bf16)0.f;
            afv[lb][mt] = t;
        }
    }

    f32x4 oacc[2][4];
#pragma unroll
    for (int i = 0; i < 2; i++)
#pragma unroll
        for (int j = 0; j < 4; j++)
#pragma unroll
            for (int r = 0; r < 4; r++) oacc[i][j][r] = 0.f;

#pragma unroll
    for (int m = 0; m < 2; m++) {
        const int row = 2 * wave + m;
        gld_lds16((const bf16*)(mv + (size_t)(b0 + row) * 8192 + gk * 1024 + gi4),
                  (bf16*)&Vl32[0][row * 256]);
    }
#pragma unroll
    for (int m = 0; m < 2; m++) {
        const int row = 2 * wave + m;
        gld_lds16((const bf16*)(mv + (size_t)(b0 + row) * 8192 + gk * 1024 + 32 + gi4),
                  (bf16*)&Vl32[1][row * 256]);
    }

    for (int sp = 0; sp < 32; ++sp) {
        const int ni = (sp + 2 < 32) ? sp * 32 + 64 : 0;
        const int cb = sp % 3, nb = (sp + 2) % 3;

        bf16x8 wb[2][4];
#pragma unroll
        for (int hh = 0; hh < 2; hh++) {
            const int h = h0 + hh;
#pragma unroll
            for (int dt = 0; dt < 4; dt++)
                wb[hh][dt] = *(const bf16x8*)(Wvf +
                    ((((size_t)h * 32 + sp) * 4 + dt) * 512 + lane * 8));
        }
        __builtin_amdgcn_sched_barrier(0);

#pragma unroll
        for (int m = 0; m < 2; m++) {
            const int row = 2 * wave + m;
            gld_lds16((const bf16*)(mv + (size_t)(b0 + row) * 8192 + gk * 1024 + ni + gi4),
                      (bf16*)&Vl32[nb][row * 256]);
        }
        __builtin_amdgcn_sched_barrier(0);

        asm volatile("s_waitcnt vmcnt(12)" ::: "memory");
        __builtin_amdgcn_sched_barrier(0);
#pragma unroll
        for (int lb = 0; lb < 2; lb++) {
            const int row = 2 * wave + lb;
            const int il = (q & 1) * 16 + lm;
            float v[8];
#pragma unroll
            for (int k = 0; k < 8; k++) v[k] = Vl32[cb][row * 256 + k * 32 + il];
            bf16x8 avf;
#pragma unroll
            for (int k = 0; k < 8; k++) avf[k] = (bf16)v[k];
#pragma unroll
            for (int mt = 0; mt < 2; mt++) {
                f32x4 c;
                c[0] = 0.f; c[1] = 0.f; c[2] = 0.f; c[3] = 0.f;
                c = __builtin_amdgcn_mfma_f32_16x16x32_bf16(avf, afv[lb][mt], c, 0, 0, 0);
                bf16x4 o;
                o[0] = (bf16)c[0]; o[1] = (bf16)c[1]; o[2] = (bf16)c[2]; o[3] = (bf16)c[3];
                *(bf16x4*)((char*)Wl + ((((row * 16 + lm) * 32 + mt * 16 + q * 4) * 2)
                                        ^ (((row ^ lm) & 7) << 4))) = o;
            }
        }
        block_barrier();

        asm volatile("s_waitcnt vmcnt(2)" ::: "memory");
        __builtin_amdgcn_sched_barrier(0);
#pragma unroll
        for (int hh = 0; hh < 2; hh++) {
            const int h = h0 + hh;
            const bf16x8 wa = *(const bf16x8*)((char*)Wl +
                ((((lm * 16 + h) * 32 + q * 8) * 2) ^ (((lm ^ h) & 7) << 4)));
#pragma unroll
            for (int dt = 0; dt < 4; dt++)
                oacc[hh][dt] = __builtin_amdgcn_mfma_f32_16x16x32_bf16(wa, wb[hh][dt], oacc[hh][dt], 0, 0, 0);
        }
        block_barrier();
    }

#pragma unroll
    for (int hh = 0; hh < 2; hh++) {
        const int h = h0 + hh;
#pragma unroll
        for (int dt = 0; dt < 4; dt++) {
#pragma unroll
            for (int r = 0; r < 4; r++)
                OH[(size_t)(b0 + q * 4 + r) * 1024 + h * 64 + dt * 16 + lm] = (bf16)oacc[hh][dt][r];
        }
    }
}

// ---------------------------------------------------------------------------
// sigmoid gate + residual + LayerNorm. One block per row.
// ---------------------------------------------------------------------------
__global__ __launch_bounds__(256)
void gate_ln_kernel(const float* __restrict__ hs, const float* __restrict__ mo,
                    const float* __restrict__ z,  const float* __restrict__ bg,
                    const float* __restrict__ lng, const float* __restrict__ lnb,
                    float* __restrict__ out)
{
    __shared__ float s1[4], s2[4];
    const int tid = threadIdx.x;
    const size_t base = (size_t)blockIdx.x * 1024 + tid * 4;

    const float4 h4 = *(const float4*)&hs[base];
    const float4 m4 = *(const float4*)&mo[base];
    const float4 z4 = *(const float4*)&z[base];
    const float4 bg4 = *(const float4*)&bg[tid * 4];

    float a[4];
    {
        const float g0 = 1.f / (1.f + __expf(-(z4.x + bg4.x)));
        const float g1 = 1.f / (1.f + __expf(-(z4.y + bg4.y)));
        const float g2 = 1.f / (1.f + __expf(-(z4.z + bg4.z)));
        const float g3 = 1.f / (1.f + __expf(-(z4.w + bg4.w)));
        a[0] = h4.x + g0 * m4.x;
        a[1] = h4.y + g1 * m4.y;
        a[2] = h4.z + g2 * m4.z;
        a[3] = h4.w + g3 * m4.w;
    }
    float sum = a[0] + a[1] + a[2] + a[3];
    float sq  = a[0]*a[0] + a[1]*a[1] + a[2]*a[2] + a[3]*a[3];
#pragma unroll
    for (int off = 32; off >= 1; off >>= 1) {
        sum += __shfl_xor(sum, off);
        sq  += __shfl_xor(sq,  off);
    }
    const int wave = tid >> 6;
    if ((tid & 63) == 0) { s1[wave] = sum; s2[wave] = sq; }
    __syncthreads();
    const float mean = (s1[0] + s1[1] + s1[2] + s1[3]) * (1.f / 1024.f);
    const float var  = (s2[0] + s2[1] + s2[2] + s2[3]) * (1.f / 1024.f) - mean * mean;
    const float inv  = rsqrtf(var + 1e-5f);

    const float4 g4 = *(const float4*)&lng[tid * 4];
    const float4 b4 = *(const float4*)&lnb[tid * 4];
    float4 o;
    o.x = (a[0] - mean) * inv * g4.x + b4.x;
    o.y = (a[1] - mean) * inv * g4.y + b4.y;
    o.z = (a[2] - mean) * inv * g4.z + b4.z;
    o.w = (a[3] - mean) * inv * g4.w + b4.w;
    *(float4*)&out[base] = o;
}

// ---------------------------------------------------------------------------
extern "C" void kernel_launch(void* const* d_in, const int* in_sizes, int n_in,
                              void* d_out, int out_size, void* d_ws, size_t ws_size,
                              hipStream_t stream)
{
    const float* hs  = (const float*)d_in[0];
    const float* mk  = (const float*)d_in[1];
    const float* mv  = (const float*)d_in[2];
    const float* Wq  = (const float*)d_in[3];
    const float* Wk  = (const float*)d_in[4];
    const float* Wv  = (const float*)d_in[5];
    const float* Wo  = (const float*)d_in[6];
    const float* Wg  = (const float*)d_in[7];
    const float* bg  = (const float*)d_in[8];
    const float* lng = (const float*)d_in[9];
    const float* lnb = (const float*)d_in[10];
    float* out = (float*)d_out;

    const int B = 8192;
    const dim3 tb(256);

    char* ws = (char*)d_ws;
    bf16*  Wq_t = (bf16*)(ws);                        // 2 MB  (1024x1024, N x K)
    bf16*  Wv_t = (bf16*)(ws + ((size_t)2  << 20));   // 2 MB
    bf16*  Wo_t = (bf16*)(ws + ((size_t)4  << 20));   // 2 MB
    bf16*  Wg_t = (bf16*)(ws + ((size_t)6  << 20));   // 4 MB  (1024x2048)
    bf16*  Wk_b = (bf16*)(ws + ((size_t)10 << 20));   // 2 MB  (1024x1024, NOT transposed)
    bf16*  hs_b = (bf16*)(ws + ((size_t)12 << 20));   // 16 MB (8192x1024)
    bf16*  Qb   = (bf16*)(ws + ((size_t)28 << 20));   // 16 MB
    bf16*  OH   = (bf16*)(ws + ((size_t)44 << 20));   // 16 MB
    float* Mo   = (float*)(ws + ((size_t)60 << 20));  // 32 MB
    bf16*  Mo_b = (bf16*)(ws + ((size_t)92 << 20));   // 16 MB
    float* Zb   = (float*)(ws + ((size_t)108 << 20)); // 32 MB
    float* At   = (float*)(ws + ((size_t)140 << 20)); // 4 MB  (8192x16x8 fp32)
    bf16*  Wvf  = (bf16*)(ws + ((size_t)208 << 20));  // 2 MB  (fragment-major Wv)
    bf16*  Wkf  = (bf16*)(ws + ((size_t)210 << 20));  // 2 MB  (fragment-major Wk, 32-i)
    bf16*  Qf   = (bf16*)(ws + ((size_t)212 << 20));  // 16 MB (fragment-major Q)

    transpose_cvt<<<dim3(32, 32), tb, 0, stream>>>(Wq, Wq_t, 1024, 1024);
    transpose_cvt<<<dim3(32, 32), tb, 0, stream>>>(Wv, Wv_t, 1024, 1024);
    transpose_cvt<<<dim3(32, 32), tb, 0, stream>>>(Wo, Wo_t, 1024, 1024);
    transpose_cvt<<<dim3(32, 64), tb, 0, stream>>>(Wg, Wg_t, 2048, 1024);
    cvt_bf16<<<dim3(1024 * 1024 / 8 / 256), tb, 0, stream>>>(Wk, Wk_b, 1024 * 1024 / 8);
    cvt_bf16<<<dim3(B * 1024 / 8 / 256), tb, 0, stream>>>(hs, hs_b, B * 1024 / 8);
    repack_wv<<<dim3(512), tb, 0, stream>>>(Wv_t, Wvf);
    repack_wk2<<<dim3(512), tb, 0, stream>>>(Wk_b, Wkf);

    // Q = hs @ Wq -> bf16 (B x 1024)
    gemm_a97<false><<<dim3(8, 64, 1), tb, 0, stream>>>(
        hs_b, nullptr, Wq_t, nullptr, Qb,
        1024, 1024, 1024, 0, 1024, 1024, 0, 0, 0);
    // fragment-major Q for the score kernel
    repack_q<<<dim3(4096), tb, 0, stream>>>(Qb, Qf);
    // fused: U-gen + scores + softmax -> attn (B x 16 x 8 fp32)
    score_attn<<<dim3(B / 16), dim3(512), 0, stream>>>(Qf, Wkf, mk, At);
    // fused: W_mix-gen + V-proj -> OH (B x 1024 bf16)
    apply_attn<<<dim3(B / 16), dim3(512), 0, stream>>>(At, mv, Wvf, OH);
    // memory_out = OH @ Wo -> fp32 Mo + bf16 Mo_b
    gemm_a97<false><<<dim3(8, 64, 1), tb, 0, stream>>>(
        OH, nullptr, Wo_t, Mo, Mo_b,
        1024, 1024, 1024, 0, 1024, 1024, 0, 0, 0);
    // z = [hs, Mo] @ Wg -> fp32
    gemm_a97<true><<<dim3(8, 64, 1), tb, 0, stream>>>(
        hs_b, Mo_b, Wg_t, Zb, nullptr,
        2048, 1024, 1024, 1024, 2048, 1024, 0, 0, 0);
    // gate + residual + LayerNorm
    gate_ln_kernel<<<dim3(B), tb, 0, stream>>>(
        hs, Mo, Zb, bg, lng, lnb, out);
}

// Round 18
// 402.425 us; speedup vs baseline: 1.3080x; 1.0099x over previous
//
#include <hip/hip_runtime.h>
#include <hip/hip_bf16.h>

typedef __bf16 bf16;
typedef __bf16 bf16x8 __attribute__((ext_vector_type(8)));
typedef __bf16 bf16x4 __attribute__((ext_vector_type(4)));
typedef float  f32x4  __attribute__((ext_vector_type(4)));

// ---------------------------------------------------------------------------
// raw barrier: flush LDS ops (lgkmcnt), DO NOT drain vmcnt — in-flight global
// loads / global_load_lds survive the barrier.
// ---------------------------------------------------------------------------
__device__ __forceinline__ void block_barrier()
{
    asm volatile("s_waitcnt lgkmcnt(0)\n\ts_barrier" ::: "memory");
}

// ---------------------------------------------------------------------------
// async global->LDS 16B per lane: LDS dst = wave-uniform base + lane*16B
// ---------------------------------------------------------------------------
#if defined(__has_builtin)
#if __has_builtin(__builtin_amdgcn_global_load_lds)
#define HAS_GLD 1
#endif
#endif
#ifndef HAS_GLD
#define HAS_GLD 0
#endif

__device__ __forceinline__ void gld_lds16(const bf16* g, bf16* lds_base)
{
#if HAS_GLD
    __builtin_amdgcn_global_load_lds(
        (const __attribute__((address_space(1))) void*)g,
        (__attribute__((address_space(3))) void*)lds_base, 16, 0, 0);
#else
    *(bf16x8*)(lds_base + (threadIdx.x & 63) * 8) = *(const bf16x8*)g;
#endif
}

// ---------------------------------------------------------------------------
// Weight transpose + fp32->bf16: src (K,N) row-major -> dst (N,K)
// ---------------------------------------------------------------------------
__global__ __launch_bounds__(256)
void transpose_cvt(const float* __restrict__ src, bf16* __restrict__ dst, int K, int N)
{
    __shared__ float t[32][33];
    const int bx = blockIdx.x, by = blockIdx.y, tid = threadIdx.x;
    const int c = tid & 31, r0 = tid >> 5;
#pragma unroll
    for (int p = 0; p < 4; p++) {
        int r = r0 + p * 8;
        t[r][c] = src[(size_t)(by * 32 + r) * N + bx * 32 + c];
    }
    __syncthreads();
#pragma unroll
    for (int p = 0; p < 4; p++) {
        int r = r0 + p * 8;
        dst[(size_t)(bx * 32 + r) * K + by * 32 + c] = (bf16)t[c][r];
    }
}

// ---------------------------------------------------------------------------
// plain fp32 -> bf16 convert, 8 elems/thread
// ---------------------------------------------------------------------------
__global__ __launch_bounds__(256)
void cvt_bf16(const float* __restrict__ src, bf16* __restrict__ dst, int n8)
{
    const int i = blockIdx.x * 256 + threadIdx.x;
    if (i >= n8) return;
    const float4* s = (const float4*)(src + (size_t)i * 8);
    float4 a = s[0], b = s[1];
    bf16x8 o;
    o[0] = (bf16)a.x; o[1] = (bf16)a.y; o[2] = (bf16)a.z; o[3] = (bf16)a.w;
    o[4] = (bf16)b.x; o[5] = (bf16)b.y; o[6] = (bf16)b.z; o[7] = (bf16)b.w;
    *(bf16x8*)(dst + (size_t)i * 8) = o;
}

// ---------------------------------------------------------------------------
// Fragment-major repacks: one coalesced 1KB burst per (group, wave) read.
// ---------------------------------------------------------------------------
__global__ __launch_bounds__(256)
void repack_wv(const bf16* __restrict__ Wvt, bf16* __restrict__ Wvf)
{
    const int t = blockIdx.x * 256 + threadIdx.x;
    const int lane = t & 63, g = t >> 6;           // g in [0, 2048)
    const int dt = g & 3, sp = (g >> 2) & 31, h = g >> 7;
    const int lm = lane & 15, q = lane >> 4;
    const bf16x8 v = *(const bf16x8*)(Wvt + (size_t)(h * 64 + dt * 16 + lm) * 1024
                                      + sp * 32 + q * 8);
    *(bf16x8*)(Wvf + (size_t)g * 512 + lane * 8) = v;
}

// Qf[((bt*16 + h)*2 + half)*512 + lane*8] = Qb[(bt*16+lm)*1024 + h*64 + half*32 + q*8]
__global__ __launch_bounds__(256)
void repack_q(const bf16* __restrict__ Qb, bf16* __restrict__ Qf)
{
    const int t = blockIdx.x * 256 + threadIdx.x;  // 1M threads
    const int lane = t & 63, g = t >> 6;           // g in [0, 16384)
    const int half = g & 1, h = (g >> 1) & 15, bt = g >> 5;
    const int lm = lane & 15, q = lane >> 4;
    const bf16x8 v = *(const bf16x8*)(Qb + (size_t)(bt * 16 + lm) * 1024
                                      + h * 64 + half * 32 + q * 8);
    *(bf16x8*)(Qf + (size_t)g * 512 + lane * 8) = v;
}

// Wkf2[(((sp*2+mt)*16+h)*2+half)*512 + lane*8] =
//     Wkb[(sp*32+mt*16+lm)*1024 + h*64 + half*32 + q*8]   (32-i superstep frags)
__global__ __launch_bounds__(256)
void repack_wk2(const bf16* __restrict__ Wkb, bf16* __restrict__ Wkf)
{
    const int t = blockIdx.x * 256 + threadIdx.x;  // 131072 threads
    const int lane = t & 63, g = t >> 6;           // g in [0, 2048)
    const int half = g & 1, h = (g >> 1) & 15, mt = (g >> 5) & 1, sp = g >> 6;
    const int lm = lane & 15, q = lane >> 4;
    const bf16x8 v = *(const bf16x8*)(Wkb + (size_t)(sp * 32 + mt * 16 + lm) * 1024
                                      + h * 64 + half * 32 + q * 8);
    *(bf16x8*)(Wkf + (size_t)g * 512 + lane * 8) = v;
}

// ---------------------------------------------------------------------------
// m97-style GEMM: C = A @ B.  A bf16 (rows via ldA), Bt bf16 (N x K, ldB).
// 128x128 tile, BK=32, global_load_lds staging, XCD swizzle (gridDim.x==8).
// Optional A2 for concat-K (gate).
// ---------------------------------------------------------------------------
template<bool TWOA>
__global__ __launch_bounds__(256)
void gemm_a97(const bf16* __restrict__ A1, const bf16* __restrict__ A2,
              const bf16* __restrict__ Bt, float* __restrict__ Cf,
              bf16* __restrict__ Cb, int Kloop, int Ksplit,
              int ldA, int ldA2, int ldB, int ldC,
              long az, long bz, long cz)
{
    __shared__ bf16 Al[128 * 32];
    __shared__ bf16 Bl[128 * 32];

    const int z = blockIdx.z;
    A1 += (size_t)z * az;
    Bt += (size_t)z * bz;
    if (Cf) Cf += (size_t)z * cz;
    if (Cb) Cb += (size_t)z * cz;

    int bx, by;
    {
        const int gy = gridDim.y;
        const int flat = blockIdx.y * gridDim.x + blockIdx.x;
        if ((gy & 7) == 0 && gridDim.x == 8) {
            const int xcd = flat & 7, slot = flat >> 3, mpx = gy >> 3;
            by = xcd * mpx + (slot >> 3);
            bx = slot & 7;
        } else { bx = blockIdx.x; by = blockIdx.y; }
    }

    const int tid = threadIdx.x;
    const int wave = tid >> 6, lane = tid & 63;
    const int m0 = by * 128, n0 = bx * 128;
    const int rl = lane >> 2;
    const int kc = (lane & 3) * 8;
    const int wm = wave >> 1, wn = wave & 1, lm = lane & 15, quad = lane >> 4;

    f32x4 acc[4][4];
#pragma unroll
    for (int i = 0; i < 4; i++)
#pragma unroll
        for (int j = 0; j < 4; j++)
#pragma unroll
            for (int r = 0; r < 4; r++) acc[i][j][r] = 0.f;

    for (int k0 = 0; k0 < Kloop; k0 += 32) {
        const bf16* Ab; int kof, ld;
        if (TWOA && k0 >= Ksplit) { Ab = A2; kof = k0 - Ksplit; ld = ldA2; }
        else                      { Ab = A1; kof = k0;          ld = ldA;  }
        const int r0 = wave * 32 + rl, r1 = r0 + 16;
        gld_lds16(Ab + (size_t)(m0 + r0) * ld + kof + kc, Al + (wave * 32) * 32);
        gld_lds16(Ab + (size_t)(m0 + r1) * ld + kof + kc, Al + (wave * 32 + 16) * 32);
        gld_lds16(Bt + (size_t)(n0 + r0) * ldB + k0 + kc, Bl + (wave * 32) * 32);
        gld_lds16(Bt + (size_t)(n0 + r1) * ldB + k0 + kc, Bl + (wave * 32 + 16) * 32);
        __syncthreads();

        bf16x8 af[4], bfr[4];
#pragma unroll
        for (int i = 0; i < 4; i++)
            af[i] = *(const bf16x8*)&Al[(wm * 64 + i * 16 + lm) * 32 + quad * 8];
#pragma unroll
        for (int j = 0; j < 4; j++)
            bfr[j] = *(const bf16x8*)&Bl[(wn * 64 + j * 16 + lm) * 32 + quad * 8];
#pragma unroll
        for (int i = 0; i < 4; i++)
#pragma unroll
            for (int j = 0; j < 4; j++)
                acc[i][j] = __builtin_amdgcn_mfma_f32_16x16x32_bf16(af[i], bfr[j], acc[i][j], 0, 0, 0);
        __syncthreads();
    }

#pragma unroll
    for (int i = 0; i < 4; i++) {
        const int rbase = m0 + wm * 64 + i * 16 + quad * 4;
#pragma unroll
        for (int j = 0; j < 4; j++) {
            const int c = n0 + wn * 64 + j * 16 + lm;
#pragma unroll
            for (int r = 0; r < 4; r++) {
                const float v = acc[i][j][r];
                const size_t idx = (size_t)(rbase + r) * ldC + c;
                if (Cf) Cf[idx] = v;
                if (Cb) Cb[idx] = (bf16)v;
            }
        }
    }
}

// ---------------------------------------------------------------------------
// Fused score kernel v5 (verified R16): register-neutral wk latency cover.
// ---------------------------------------------------------------------------
__global__ __launch_bounds__(512, 4)
void score_attn(const bf16* __restrict__ Qf, const bf16* __restrict__ Wkf,
                const float* __restrict__ mk, float* __restrict__ attn)
{
    __shared__ bf16  Ul[16 * 16 * 32]; // 16KB [b][h][32i] swz ^(((b^h)&7)<<4)
    __shared__ float Ml[2][4096];      // 2x16KB [16b][8 g4][8 k][4 i]

    const int tid  = threadIdx.x;
    const int wave = tid >> 6, lane = tid & 63;
    const int lm = lane & 15, q = lane >> 4;
    const int bt = blockIdx.x;         // rows [bt*16, bt*16+16)
    const int h0 = wave * 2;

    const int gk = lane & 7, gg4 = lane >> 3;

    // ---- persistent Q B-frags (coalesced 1KB bursts, loaded once)
    bf16x8 qf[2][2];
#pragma unroll
    for (int hh = 0; hh < 2; hh++)
#pragma unroll
        for (int half = 0; half < 2; half++)
            qf[hh][half] = *(const bf16x8*)(Qf +
                (size_t)((bt * 16 + h0 + hh) * 2 + half) * 512 + lane * 8);

    f32x4 sacc[2];
#pragma unroll
    for (int lb = 0; lb < 2; lb++)
#pragma unroll
        for (int r = 0; r < 4; r++) sacc[lb][r] = 0.f;

    // single wk register buffer (8 bf16x8 = 32 VGPR)
    bf16x8 wk[2][2][2];

    // ---- prologue: wk(0) (8 bursts), DMA(0) -> Ml[0]
#pragma unroll
    for (int hh = 0; hh < 2; hh++)
#pragma unroll
        for (int mt = 0; mt < 2; mt++)
#pragma unroll
            for (int half = 0; half < 2; half++)
                wk[hh][mt][half] = *(const bf16x8*)(Wkf +
                    (size_t)(((0 * 2 + mt) * 16 + h0 + hh) * 2 + half) * 512 + lane * 8);
#pragma unroll
    for (int m = 0; m < 2; m++) {
        const int row = 2 * wave + m;
        gld_lds16((const bf16*)(mk + (size_t)(bt * 16 + row) * 8192 + gk * 1024 + gg4 * 4),
                  (bf16*)&Ml[0][row * 256]);
    }

    for (int sp = 0; sp < 32; ++sp) {
        const int nspf = (sp + 1 < 32) ? sp + 1 : 0;  // tail wraps (data unused)
        const int ni   = nspf * 32;
        const int nb   = (sp + 1) & 1, cb = sp & 1;

        // ---- 1. DMA slice sp+1 -> Ml[nb] (own rows; youngest vmem)
#pragma unroll
        for (int m = 0; m < 2; m++) {
            const int row = 2 * wave + m;
            gld_lds16((const bf16*)(mk + (size_t)(bt * 16 + row) * 8192 + gk * 1024 + ni + gg4 * 4),
                      (bf16*)&Ml[nb][row * 256]);
        }
        __builtin_amdgcn_sched_barrier(0);

        // ---- 2. wait: only DMA(sp+1) outstanding -> wk(sp)+DMA(sp) landed
        asm volatile("s_waitcnt vmcnt(2)" ::: "memory");
        __builtin_amdgcn_sched_barrier(0);

        // ---- 3. U-gen from wk(sp) -> Ul
#pragma unroll
        for (int hh = 0; hh < 2; hh++) {
            const int h = h0 + hh;
#pragma unroll
            for (int mt = 0; mt < 2; mt++) {
                f32x4 c4;
                c4[0] = 0.f; c4[1] = 0.f; c4[2] = 0.f; c4[3] = 0.f;
                c4 = __builtin_amdgcn_mfma_f32_16x16x32_bf16(wk[hh][mt][0], qf[hh][0], c4, 0, 0, 0);
                c4 = __builtin_amdgcn_mfma_f32_16x16x32_bf16(wk[hh][mt][1], qf[hh][1], c4, 0, 0, 0);
                bf16x4 o;
                o[0] = (bf16)c4[0]; o[1] = (bf16)c4[1]; o[2] = (bf16)c4[2]; o[3] = (bf16)c4[3];
                *(bf16x4*)((char*)Ul + ((((lm * 16 + h) * 32 + mt * 16 + q * 4) * 2)
                                        ^ (((lm ^ h) & 7) << 4))) = o;
            }
        }
        __builtin_amdgcn_sched_barrier(0);

        // ---- 4. issue wk(sp+1) into the SAME regs (WAR after U-gen)
#pragma unroll
        for (int hh = 0; hh < 2; hh++)
#pragma unroll
            for (int mt = 0; mt < 2; mt++)
#pragma unroll
                for (int half = 0; half < 2; half++)
                    wk[hh][mt][half] = *(const bf16x8*)(Wkf +
                        (size_t)(((nspf * 2 + mt) * 16 + h0 + hh) * 2 + half) * 512 + lane * 8);
        __builtin_amdgcn_sched_barrier(0);

        block_barrier();   // Ul visible (lgkm only; vmem stays in flight)

        // ---- 5. score accumulate from Ml[cb] (own rows)
#pragma unroll
        for (int lb = 0; lb < 2; lb++) {
            const int bb = wave * 2 + lb;
            const bf16x8 ua = *(const bf16x8*)((char*)Ul +
                ((((bb * 16 + lm) * 32 + q * 8) * 2) ^ (((bb ^ lm) & 7) << 4)));
            const int kk = lm & 7;
            const f32x4 a0 = *(const f32x4*)&Ml[cb][bb * 256 + (q * 2) * 32 + kk * 4];
            const f32x4 a1 = *(const f32x4*)&Ml[cb][bb * 256 + (q * 2 + 1) * 32 + kk * 4];
            bf16x8 mb;
            mb[0] = (bf16)a0[0]; mb[1] = (bf16)a0[1]; mb[2] = (bf16)a0[2]; mb[3] = (bf16)a0[3];
            mb[4] = (bf16)a1[0]; mb[5] = (bf16)a1[1]; mb[6] = (bf16)a1[2]; mb[7] = (bf16)a1[3];
            sacc[lb] = __builtin_amdgcn_mfma_f32_16x16x32_bf16(ua, mb, sacc[lb], 0, 0, 0);
        }
        block_barrier();   // Ul + Ml[cb] consumed
    }

    // ---- softmax over k (cols duplicated across lm and lm+8) + store attn
#pragma unroll
    for (int lb = 0; lb < 2; lb++) {
        const size_t bb = (size_t)(bt * 16 + wave * 2 + lb);
#pragma unroll
        for (int r = 0; r < 4; r++) {
            float s = sacc[lb][r] * 0.125f;          // DH^-0.5
            float mx = s;
            mx = fmaxf(mx, __shfl_xor(mx, 1));
            mx = fmaxf(mx, __shfl_xor(mx, 2));
            mx = fmaxf(mx, __shfl_xor(mx, 4));
            mx = fmaxf(mx, __shfl_xor(mx, 8));
            const float e = __expf(s - mx);
            float d = e;
            d += __shfl_xor(d, 1);
            d += __shfl_xor(d, 2);
            d += __shfl_xor(d, 4);
            d += __shfl_xor(d, 8);                   // = 2 * true denom
            const float a = e * (2.f / d);
            if (lm < 8) attn[bb * 128 + (q * 4 + r) * 8 + lm] = a;
        }
    }
}

// ---------------------------------------------------------------------------
// Fused apply kernel v12: register-neutral wb latency cover (score-v5
// pattern).  wb(sp+1) is issued right AFTER OH(sp) consumes the regs (WAR
// reuse).  Queue order: DMA(sp+1) < wb(sp) < DMA(sp+2), so Wm-gen waits
// vmcnt(12) (DMA(sp) landed) and OH waits vmcnt(2) (wb(sp) landed with a
// FULL superstep of cover).  Same registers/LDS as v10.
// ---------------------------------------------------------------------------
__global__ __launch_bounds__(512, 4)
void apply_attn(const float* __restrict__ attn, const float* __restrict__ mv,
                const bf16* __restrict__ Wvf, bf16* __restrict__ OH)
{
    __shared__ float Vl32[3][4096];    // 3x16KB [16 rows][8 k][32 i] fp32, LINEAR
    __shared__ bf16  Wl[16 * 16 * 32]; // 16KB [b][h][32 i] swz ^(((b^h)&7)<<4)

    const int tid  = threadIdx.x;
    const int wave = tid >> 6, lane = tid & 63;
    const int lm = lane & 15, q = lane >> 4;
    const int b0 = blockIdx.x * 16;
    const int h0 = wave * 2;

    const int gk = lane >> 3, gi4 = (lane & 7) * 4;

    bf16x8 afv[2][2];
#pragma unroll
    for (int lb = 0; lb < 2; lb++) {
        const float* ap = attn + (size_t)(b0 + wave * 2 + lb) * 128 + lm * 8;
        const float4 x = *(const float4*)(ap);
        const float4 y = *(const float4*)(ap + 4);
        bf16 a8[8];
        a8[0] = (bf16)x.x; a8[1] = (bf16)x.y; a8[2] = (bf16)x.z; a8[3] = (bf16)x.w;
        a8[4] = (bf16)y.x; a8[5] = (bf16)y.y; a8[6] = (bf16)y.z; a8[7] = (bf16)y.w;
#pragma unroll
        for (int mt = 0; mt < 2; mt++) {
            bf16x8 t;
#pragma unroll
            for (int j = 0; j < 8; j++) t[j] = (q == mt) ? a8[j] : (bf16)0.f;
            afv[lb][mt] = t;
        }
    }

    f32x4 oacc[2][4];
#pragma unroll
    for (int i = 0; i < 2; i++)
#pragma unroll
        for (int j = 0; j < 4; j++)
#pragma unroll
            for (int r = 0; r < 4; r++) oacc[i][j][r] = 0.f;

    // single wb register buffer (8 bf16x8 = 32 VGPR)
    bf16x8 wb[2][4];

    // ---- prologue: DMA(0), DMA(1), then wb(0) (queue: D0 < D1 < wb0)
#pragma unroll
    for (int m = 0; m < 2; m++) {
        const int row = 2 * wave + m;
        gld_lds16((const bf16*)(mv + (size_t)(b0 + row) * 8192 + gk * 1024 + gi4),
                  (bf16*)&Vl32[0][row * 256]);
    }
#pragma unroll
    for (int m = 0; m < 2; m++) {
        const int row = 2 * wave + m;
        gld_lds16((const bf16*)(mv + (size_t)(b0 + row) * 8192 + gk * 1024 + 32 + gi4),
                  (bf16*)&Vl32[1][row * 256]);
    }
#pragma unroll
    for (int hh = 0; hh < 2; hh++) {
        const int h = h0 + hh;
#pragma unroll
        for (int dt = 0; dt < 4; dt++)
            wb[hh][dt] = *(const bf16x8*)(Wvf +
                ((((size_t)h * 32 + 0) * 4 + dt) * 512 + lane * 8));
    }

    for (int sp = 0; sp < 32; ++sp) {
        const int ni = (sp + 2 < 32) ? sp * 32 + 64 : 0;   // tail wraps (unused)
        const int nwb = (sp + 1 < 32) ? sp + 1 : 0;        // tail wraps (unused)
        const int cb = sp % 3, nb = (sp + 2) % 3;

        // ---- 1. DMA slice sp+2 (youngest)
#pragma unroll
        for (int m = 0; m < 2; m++) {
            const int row = 2 * wave + m;
            gld_lds16((const bf16*)(mv + (size_t)(b0 + row) * 8192 + gk * 1024 + ni + gi4),
                      (bf16*)&Vl32[nb][row * 256]);
        }
        __builtin_amdgcn_sched_barrier(0);

        // ---- 2. wait own DMA(sp): younger = DMA(sp+1)2 + wb(sp)8 + DMA(sp+2)2
        asm volatile("s_waitcnt vmcnt(12)" ::: "memory");
        __builtin_amdgcn_sched_barrier(0);

        // ---- 3. Wm-gen from Vl32[cb] (own rows) -> Wl
#pragma unroll
        for (int lb = 0; lb < 2; lb++) {
            const int row = 2 * wave + lb;
            const int il = (q & 1) * 16 + lm;
            float v[8];
#pragma unroll
            for (int k = 0; k < 8; k++) v[k] = Vl32[cb][row * 256 + k * 32 + il];
            bf16x8 avf;
#pragma unroll
            for (int k = 0; k < 8; k++) avf[k] = (bf16)v[k];
#pragma unroll
            for (int mt = 0; mt < 2; mt++) {
                f32x4 c;
                c[0] = 0.f; c[1] = 0.f; c[2] = 0.f; c[3] = 0.f;
                c = __builtin_amdgcn_mfma_f32_16x16x32_bf16(avf, afv[lb][mt], c, 0, 0, 0);
                bf16x4 o;
                o[0] = (bf16)c[0]; o[1] = (bf16)c[1]; o[2] = (bf16)c[2]; o[3] = (bf16)c[3];
                *(bf16x4*)((char*)Wl + ((((row * 16 + lm) * 32 + mt * 16 + q * 4) * 2)
                                        ^ (((row ^ lm) & 7) << 4))) = o;
            }
        }
        block_barrier();   // Wl visible (lgkm only; vmem stays in flight)

        // ---- 4. wait wb(sp) (full superstep of cover): younger = DMA(sp+2)2
        asm volatile("s_waitcnt vmcnt(2)" ::: "memory");
        __builtin_amdgcn_sched_barrier(0);

        // ---- 5. OH: Wl reads + wb(sp) regs
#pragma unroll
        for (int hh = 0; hh < 2; hh++) {
            const int h = h0 + hh;
            const bf16x8 wa = *(const bf16x8*)((char*)Wl +
                ((((lm * 16 + h) * 32 + q * 8) * 2) ^ (((lm ^ h) & 7) << 4)));
#pragma unroll
            for (int dt = 0; dt < 4; dt++)
                oacc[hh][dt] = __builtin_amdgcn_mfma_f32_16x16x32_bf16(wa, wb[hh][dt], oacc[hh][dt], 0, 0, 0);
        }
        __builtin_amdgcn_sched_barrier(0);

        // ---- 6. issue wb(sp+1) into the SAME regs (WAR after OH)
#pragma unroll
        for (int hh = 0; hh < 2; hh++) {
            const int h = h0 + hh;
#pragma unroll
            for (int dt = 0; dt < 4; dt++)
                wb[hh][dt] = *(const bf16x8*)(Wvf +
                    ((((size_t)h * 32 + nwb) * 4 + dt) * 512 + lane * 8));
        }
        __builtin_amdgcn_sched_barrier(0);

        block_barrier();   // Wl consumed; safe to overwrite next superstep
    }

    // ---- store OH (rows b = q*4+r, cols h*64 + dt*16 + lm)
#pragma unroll
    for (int hh = 0; hh < 2; hh++) {
        const int h = h0 + hh;
#pragma unroll
        for (int dt = 0; dt < 4; dt++) {
#pragma unroll
            for (int r = 0; r < 4; r++)
                OH[(size_t)(b0 + q * 4 + r) * 1024 + h * 64 + dt * 16 + lm] = (bf16)oacc[hh][dt][r];
        }
    }
}

// ---------------------------------------------------------------------------
// sigmoid gate + residual + LayerNorm. One block per row.
// ---------------------------------------------------------------------------
__global__ __launch_bounds__(256)
void gate_ln_kernel(const float* __restrict__ hs, const float* __restrict__ mo,
                    const float* __restrict__ z,  const float* __restrict__ bg,
                    const float* __restrict__ lng, const float* __restrict__ lnb,
                    float* __restrict__ out)
{
    __shared__ float s1[4], s2[4];
    const int tid = threadIdx.x;
    const size_t base = (size_t)blockIdx.x * 1024 + tid * 4;

    const float4 h4 = *(const float4*)&hs[base];
    const float4 m4 = *(const float4*)&mo[base];
    const float4 z4 = *(const float4*)&z[base];
    const float4 bg4 = *(const float4*)&bg[tid * 4];

    float a[4];
    {
        const float g0 = 1.f / (1.f + __expf(-(z4.x + bg4.x)));
        const float g1 = 1.f / (1.f + __expf(-(z4.y + bg4.y)));
        const float g2 = 1.f / (1.f + __expf(-(z4.z + bg4.z)));
        const float g3 = 1.f / (1.f + __expf(-(z4.w + bg4.w)));
        a[0] = h4.x + g0 * m4.x;
        a[1] = h4.y + g1 * m4.y;
        a[2] = h4.z + g2 * m4.z;
        a[3] = h4.w + g3 * m4.w;
    }
    float sum = a[0] + a[1] + a[2] + a[3];
    float sq  = a[0]*a[0] + a[1]*a[1] + a[2]*a[2] + a[3]*a[3];
#pragma unroll
    for (int off = 32; off >= 1; off >>= 1) {
        sum += __shfl_xor(sum, off);
        sq  += __shfl_xor(sq,  off);
    }
    const int wave = tid >> 6;
    if ((tid & 63) == 0) { s1[wave] = sum; s2[wave] = sq; }
    __syncthreads();
    const float mean = (s1[0] + s1[1] + s1[2] + s1[3]) * (1.f / 1024.f);
    const float var  = (s2[0] + s2[1] + s2[2] + s2[3]) * (1.f / 1024.f) - mean * mean;
    const float inv  = rsqrtf(var + 1e-5f);

    const float4 g4 = *(const float4*)&lng[tid * 4];
    const float4 b4 = *(const float4*)&lnb[tid * 4];
    float4 o;
    o.x = (a[0] - mean) * inv * g4.x + b4.x;
    o.y = (a[1] - mean) * inv * g4.y + b4.y;
    o.z = (a[2] - mean) * inv * g4.z + b4.z;
    o.w = (a[3] - mean) * inv * g4.w + b4.w;
    *(float4*)&out[base] = o;
}

// ---------------------------------------------------------------------------
extern "C" void kernel_launch(void* const* d_in, const int* in_sizes, int n_in,
                              void* d_out, int out_size, void* d_ws, size_t ws_size,
                              hipStream_t stream)
{
    const float* hs  = (const float*)d_in[0];
    const float* mk  = (const float*)d_in[1];
    const float* mv  = (const float*)d_in[2];
    const float* Wq  = (const float*)d_in[3];
    const float* Wk  = (const float*)d_in[4];
    const float* Wv  = (const float*)d_in[5];
    const float* Wo  = (const float*)d_in[6];
    const float* Wg  = (const float*)d_in[7];
    const float* bg  = (const float*)d_in[8];
    const float* lng = (const float*)d_in[9];
    const float* lnb = (const float*)d_in[10];
    float* out = (float*)d_out;

    const int B = 8192;
    const dim3 tb(256);

    char* ws = (char*)d_ws;
    bf16*  Wq_t = (bf16*)(ws);                        // 2 MB  (1024x1024, N x K)
    bf16*  Wv_t = (bf16*)(ws + ((size_t)2  << 20));   // 2 MB
    bf16*  Wo_t = (bf16*)(ws + ((size_t)4  << 20));   // 2 MB
    bf16*  Wg_t = (bf16*)(ws + ((size_t)6  << 20));   // 4 MB  (1024x2048)
    bf16*  Wk_b = (bf16*)(ws + ((size_t)10 << 20));   // 2 MB  (1024x1024, NOT transposed)
    bf16*  hs_b = (bf16*)(ws + ((size_t)12 << 20));   // 16 MB (8192x1024)
    bf16*  Qb   = (bf16*)(ws + ((size_t)28 << 20));   // 16 MB
    bf16*  OH   = (bf16*)(ws + ((size_t)44 << 20));   // 16 MB
    float* Mo   = (float*)(ws + ((size_t)60 << 20));  // 32 MB
    bf16*  Mo_b = (bf16*)(ws + ((size_t)92 << 20));   // 16 MB
    float* Zb   = (float*)(ws + ((size_t)108 << 20)); // 32 MB
    float* At   = (float*)(ws + ((size_t)140 << 20)); // 4 MB  (8192x16x8 fp32)
    bf16*  Wvf  = (bf16*)(ws + ((size_t)208 << 20));  // 2 MB  (fragment-major Wv)
    bf16*  Wkf  = (bf16*)(ws + ((size_t)210 << 20));  // 2 MB  (fragment-major Wk, 32-i)
    bf16*  Qf   = (bf16*)(ws + ((size_t)212 << 20));  // 16 MB (fragment-major Q)

    transpose_cvt<<<dim3(32, 32), tb, 0, stream>>>(Wq, Wq_t, 1024, 1024);
    transpose_cvt<<<dim3(32, 32), tb, 0, stream>>>(Wv, Wv_t, 1024, 1024);
    transpose_cvt<<<dim3(32, 32), tb, 0, stream>>>(Wo, Wo_t, 1024, 1024);
    transpose_cvt<<<dim3(32, 64), tb, 0, stream>>>(Wg, Wg_t, 2048, 1024);
    cvt_bf16<<<dim3(1024 * 1024 / 8 / 256), tb, 0, stream>>>(Wk, Wk_b, 1024 * 1024 / 8);
    cvt_bf16<<<dim3(B * 1024 / 8 / 256), tb, 0, stream>>>(hs, hs_b, B * 1024 / 8);
    repack_wv<<<dim3(512), tb, 0, stream>>>(Wv_t, Wvf);
    repack_wk2<<<dim3(512), tb, 0, stream>>>(Wk_b, Wkf);

    // Q = hs @ Wq -> bf16 (B x 1024)
    gemm_a97<false><<<dim3(8, 64, 1), tb, 0, stream>>>(
        hs_b, nullptr, Wq_t, nullptr, Qb,
        1024, 1024, 1024, 0, 1024, 1024, 0, 0, 0);
    // fragment-major Q for the score kernel
    repack_q<<<dim3(4096), tb, 0, stream>>>(Qb, Qf);
    // fused: U-gen + scores + softmax -> attn (B x 16 x 8 fp32)
    score_attn<<<dim3(B / 16), dim3(512), 0, stream>>>(Qf, Wkf, mk, At);
    // fused: W_mix-gen + V-proj -> OH (B x 1024 bf16)
    apply_attn<<<dim3(B / 16), dim3(512), 0, stream>>>(At, mv, Wvf, OH);
    // memory_out = OH @ Wo -> fp32 Mo + bf16 Mo_b
    gemm_a97<false><<<dim3(8, 64, 1), tb, 0, stream>>>(
        OH, nullptr, Wo_t, Mo, Mo_b,
        1024, 1024, 1024, 0, 1024, 1024, 0, 0, 0);
    // z = [hs, Mo] @ Wg -> fp32
    gemm_a97<true><<<dim3(8, 64, 1), tb, 0, stream>>>(
        hs_b, Mo_b, Wg_t, Zb, nullptr,
        2048, 1024, 1024, 1024, 2048, 1024, 0, 0, 0);
    // gate + residual + LayerNorm
    gate_ln_kernel<<<dim3(B), tb, 0, stream>>>(
        hs, Mo, Zb, bg, lng, lnb, out);
}

// Round 19
// 385.796 us; speedup vs baseline: 1.3643x; 1.0431x over previous
//
#include <hip/hip_runtime.h>
#include <hip/hip_bf16.h>

typedef __bf16 bf16;
typedef __bf16 bf16x8 __attribute__((ext_vector_type(8)));
typedef __bf16 bf16x4 __attribute__((ext_vector_type(4)));
typedef float  f32x4  __attribute__((ext_vector_type(4)));

// ---------------------------------------------------------------------------
// raw barrier: flush LDS ops (lgkmcnt), DO NOT drain vmcnt — in-flight global
// loads / global_load_lds survive the barrier.
// ---------------------------------------------------------------------------
__device__ __forceinline__ void block_barrier()
{
    asm volatile("s_waitcnt lgkmcnt(0)\n\ts_barrier" ::: "memory");
}

// ---------------------------------------------------------------------------
// async global->LDS 16B per lane: LDS dst = wave-uniform base + lane*16B
// ---------------------------------------------------------------------------
#if defined(__has_builtin)
#if __has_builtin(__builtin_amdgcn_global_load_lds)
#define HAS_GLD 1
#endif
#endif
#ifndef HAS_GLD
#define HAS_GLD 0
#endif

__device__ __forceinline__ void gld_lds16(const bf16* g, bf16* lds_base)
{
#if HAS_GLD
    __builtin_amdgcn_global_load_lds(
        (const __attribute__((address_space(1))) void*)g,
        (__attribute__((address_space(3))) void*)lds_base, 16, 0, 0);
#else
    *(bf16x8*)(lds_base + (threadIdx.x & 63) * 8) = *(const bf16x8*)g;
#endif
}

// ---------------------------------------------------------------------------
// Merged preprocessing kernel (one launch replaces 7):
//   [0,1024)      : Wq transpose+cvt -> Wq_t  (N x K)
//   [1024,2048)   : Wo transpose+cvt -> Wo_t
//   [2048,4096)   : Wg transpose+cvt -> Wg_t  (2048 x 1024 src)
//   [4096,8192)   : hs fp32 -> bf16 (hs_b)
//   [8192,8704)   : Wvf fragment-major DIRECT from Wv (composed transpose)
//   [8704,9216)   : Wkf fragment-major DIRECT from Wk (cvt only)
// All regions independent; whole blocks take one branch (uniform barriers).
// ---------------------------------------------------------------------------
__global__ __launch_bounds__(256)
void preprocess(const float* __restrict__ Wq, const float* __restrict__ Wo,
                const float* __restrict__ Wg, const float* __restrict__ hs,
                const float* __restrict__ Wv, const float* __restrict__ Wk,
                bf16* __restrict__ Wq_t, bf16* __restrict__ Wo_t,
                bf16* __restrict__ Wg_t, bf16* __restrict__ hs_b,
                bf16* __restrict__ Wvf,  bf16* __restrict__ Wkf)
{
    const int b = blockIdx.x, tid = threadIdx.x;

    if (b < 4096) {
        // ---- transpose+cvt regions (verified transpose_cvt body)
        __shared__ float t[32][33];
        const float* src; bf16* dst; int bx, by, K, N;
        if (b < 1024)      { src = Wq; dst = Wq_t; const int l = b;        bx = l & 31; by = l >> 5; K = 1024; N = 1024; }
        else if (b < 2048) { src = Wo; dst = Wo_t; const int l = b - 1024; bx = l & 31; by = l >> 5; K = 1024; N = 1024; }
        else               { src = Wg; dst = Wg_t; const int l = b - 2048; bx = l & 31; by = l >> 5; K = 2048; N = 1024; }
        const int c = tid & 31, r0 = tid >> 5;
#pragma unroll
        for (int p = 0; p < 4; p++) {
            const int r = r0 + p * 8;
            t[r][c] = src[(size_t)(by * 32 + r) * N + bx * 32 + c];
        }
        __syncthreads();
#pragma unroll
        for (int p = 0; p < 4; p++) {
            const int r = r0 + p * 8;
            dst[(size_t)(bx * 32 + r) * K + by * 32 + c] = (bf16)t[c][r];
        }
    } else if (b < 8192) {
        // ---- hs fp32 -> bf16, 8 elems/thread (verified cvt_bf16 body)
        const int i = (b - 4096) * 256 + tid;      // < 1048576 = 8192*1024/8
        const float4* s = (const float4*)(hs + (size_t)i * 8);
        const float4 a = s[0], d = s[1];
        bf16x8 o;
        o[0] = (bf16)a.x; o[1] = (bf16)a.y; o[2] = (bf16)a.z; o[3] = (bf16)a.w;
        o[4] = (bf16)d.x; o[5] = (bf16)d.y; o[6] = (bf16)d.z; o[7] = (bf16)d.w;
        *(bf16x8*)(hs_b + (size_t)i * 8) = o;
    } else if (b < 8704) {
        // ---- Wvf direct: Wvf[g*512+lane*8+j] = (bf16)Wv[(sp*32+q*8+j)*1024
        //                                              + h*64 + dt*16 + lm]
        const int t2 = (b - 8192) * 256 + tid;
        const int lane = t2 & 63, g = t2 >> 6;     // g in [0, 2048)
        const int dt = g & 3, sp = (g >> 2) & 31, h = g >> 7;
        const int lm = lane & 15, q = lane >> 4;
        bf16x8 o;
#pragma unroll
        for (int j = 0; j < 8; j++)
            o[j] = (bf16)Wv[(size_t)(sp * 32 + q * 8 + j) * 1024 + h * 64 + dt * 16 + lm];
        *(bf16x8*)(Wvf + (size_t)g * 512 + lane * 8) = o;
    } else {
        // ---- Wkf direct: Wkf[g*512+lane*8+j] = (bf16)Wk[(spw*32+mt*16+lm)*1024
        //                                              + h*64 + half*32 + q*8 + j]
        const int t2 = (b - 8704) * 256 + tid;
        const int lane = t2 & 63, g = t2 >> 6;     // g in [0, 2048)
        const int half = g & 1, h = (g >> 1) & 15, mt = (g >> 5) & 1, spw = g >> 6;
        const int lm = lane & 15, q = lane >> 4;
        const float* s = Wk + (size_t)(spw * 32 + mt * 16 + lm) * 1024
                            + h * 64 + half * 32 + q * 8;
        const f32x4 a = *(const f32x4*)s;
        const f32x4 d = *(const f32x4*)(s + 4);
        bf16x8 o;
        o[0] = (bf16)a[0]; o[1] = (bf16)a[1]; o[2] = (bf16)a[2]; o[3] = (bf16)a[3];
        o[4] = (bf16)d[0]; o[5] = (bf16)d[1]; o[6] = (bf16)d[2]; o[7] = (bf16)d[3];
        *(bf16x8*)(Wkf + (size_t)g * 512 + lane * 8) = o;
    }
}

// Qf[((bt*16 + h)*2 + half)*512 + lane*8] = Qb[(bt*16+lm)*1024 + h*64 + half*32 + q*8]
__global__ __launch_bounds__(256)
void repack_q(const bf16* __restrict__ Qb, bf16* __restrict__ Qf)
{
    const int t = blockIdx.x * 256 + threadIdx.x;  // 1M threads
    const int lane = t & 63, g = t >> 6;           // g in [0, 16384)
    const int half = g & 1, h = (g >> 1) & 15, bt = g >> 5;
    const int lm = lane & 15, q = lane >> 4;
    const bf16x8 v = *(const bf16x8*)(Qb + (size_t)(bt * 16 + lm) * 1024
                                      + h * 64 + half * 32 + q * 8);
    *(bf16x8*)(Qf + (size_t)g * 512 + lane * 8) = v;
}

// ---------------------------------------------------------------------------
// m97-style GEMM: C = A @ B.  A bf16 (rows via ldA), Bt bf16 (N x K, ldB).
// 128x128 tile, BK=32, global_load_lds staging, XCD swizzle (gridDim.x==8).
// Optional A2 for concat-K (gate).
// ---------------------------------------------------------------------------
template<bool TWOA>
__global__ __launch_bounds__(256)
void gemm_a97(const bf16* __restrict__ A1, const bf16* __restrict__ A2,
              const bf16* __restrict__ Bt, float* __restrict__ Cf,
              bf16* __restrict__ Cb, int Kloop, int Ksplit,
              int ldA, int ldA2, int ldB, int ldC,
              long az, long bz, long cz)
{
    __shared__ bf16 Al[128 * 32];
    __shared__ bf16 Bl[128 * 32];

    const int z = blockIdx.z;
    A1 += (size_t)z * az;
    Bt += (size_t)z * bz;
    if (Cf) Cf += (size_t)z * cz;
    if (Cb) Cb += (size_t)z * cz;

    int bx, by;
    {
        const int gy = gridDim.y;
        const int flat = blockIdx.y * gridDim.x + blockIdx.x;
        if ((gy & 7) == 0 && gridDim.x == 8) {
            const int xcd = flat & 7, slot = flat >> 3, mpx = gy >> 3;
            by = xcd * mpx + (slot >> 3);
            bx = slot & 7;
        } else { bx = blockIdx.x; by = blockIdx.y; }
    }

    const int tid = threadIdx.x;
    const int wave = tid >> 6, lane = tid & 63;
    const int m0 = by * 128, n0 = bx * 128;
    const int rl = lane >> 2;
    const int kc = (lane & 3) * 8;
    const int wm = wave >> 1, wn = wave & 1, lm = lane & 15, quad = lane >> 4;

    f32x4 acc[4][4];
#pragma unroll
    for (int i = 0; i < 4; i++)
#pragma unroll
        for (int j = 0; j < 4; j++)
#pragma unroll
            for (int r = 0; r < 4; r++) acc[i][j][r] = 0.f;

    for (int k0 = 0; k0 < Kloop; k0 += 32) {
        const bf16* Ab; int kof, ld;
        if (TWOA && k0 >= Ksplit) { Ab = A2; kof = k0 - Ksplit; ld = ldA2; }
        else                      { Ab = A1; kof = k0;          ld = ldA;  }
        const int r0 = wave * 32 + rl, r1 = r0 + 16;
        gld_lds16(Ab + (size_t)(m0 + r0) * ld + kof + kc, Al + (wave * 32) * 32);
        gld_lds16(Ab + (size_t)(m0 + r1) * ld + kof + kc, Al + (wave * 32 + 16) * 32);
        gld_lds16(Bt + (size_t)(n0 + r0) * ldB + k0 + kc, Bl + (wave * 32) * 32);
        gld_lds16(Bt + (size_t)(n0 + r1) * ldB + k0 + kc, Bl + (wave * 32 + 16) * 32);
        __syncthreads();

        bf16x8 af[4], bfr[4];
#pragma unroll
        for (int i = 0; i < 4; i++)
            af[i] = *(const bf16x8*)&Al[(wm * 64 + i * 16 + lm) * 32 + quad * 8];
#pragma unroll
        for (int j = 0; j < 4; j++)
            bfr[j] = *(const bf16x8*)&Bl[(wn * 64 + j * 16 + lm) * 32 + quad * 8];
#pragma unroll
        for (int i = 0; i < 4; i++)
#pragma unroll
            for (int j = 0; j < 4; j++)
                acc[i][j] = __builtin_amdgcn_mfma_f32_16x16x32_bf16(af[i], bfr[j], acc[i][j], 0, 0, 0);
        __syncthreads();
    }

#pragma unroll
    for (int i = 0; i < 4; i++) {
        const int rbase = m0 + wm * 64 + i * 16 + quad * 4;
#pragma unroll
        for (int j = 0; j < 4; j++) {
            const int c = n0 + wn * 64 + j * 16 + lm;
#pragma unroll
            for (int r = 0; r < 4; r++) {
                const float v = acc[i][j][r];
                const size_t idx = (size_t)(rbase + r) * ldC + c;
                if (Cf) Cf[idx] = v;
                if (Cb) Cb[idx] = (bf16)v;
            }
        }
    }
}

// ---------------------------------------------------------------------------
// Fused score kernel v5 (verified R16/R18): register-neutral wk latency cover.
// ---------------------------------------------------------------------------
__global__ __launch_bounds__(512, 4)
void score_attn(const bf16* __restrict__ Qf, const bf16* __restrict__ Wkf,
                const float* __restrict__ mk, float* __restrict__ attn)
{
    __shared__ bf16  Ul[16 * 16 * 32]; // 16KB [b][h][32i] swz ^(((b^h)&7)<<4)
    __shared__ float Ml[2][4096];      // 2x16KB [16b][8 g4][8 k][4 i]

    const int tid  = threadIdx.x;
    const int wave = tid >> 6, lane = tid & 63;
    const int lm = lane & 15, q = lane >> 4;
    const int bt = blockIdx.x;         // rows [bt*16, bt*16+16)
    const int h0 = wave * 2;

    const int gk = lane & 7, gg4 = lane >> 3;

    // ---- persistent Q B-frags (coalesced 1KB bursts, loaded once)
    bf16x8 qf[2][2];
#pragma unroll
    for (int hh = 0; hh < 2; hh++)
#pragma unroll
        for (int half = 0; half < 2; half++)
            qf[hh][half] = *(const bf16x8*)(Qf +
                (size_t)((bt * 16 + h0 + hh) * 2 + half) * 512 + lane * 8);

    f32x4 sacc[2];
#pragma unroll
    for (int lb = 0; lb < 2; lb++)
#pragma unroll
        for (int r = 0; r < 4; r++) sacc[lb][r] = 0.f;

    // single wk register buffer (8 bf16x8 = 32 VGPR)
    bf16x8 wk[2][2][2];

    // ---- prologue: wk(0) (8 bursts), DMA(0) -> Ml[0]
#pragma unroll
    for (int hh = 0; hh < 2; hh++)
#pragma unroll
        for (int mt = 0; mt < 2; mt++)
#pragma unroll
            for (int half = 0; half < 2; half++)
                wk[hh][mt][half] = *(const bf16x8*)(Wkf +
                    (size_t)(((0 * 2 + mt) * 16 + h0 + hh) * 2 + half) * 512 + lane * 8);
#pragma unroll
    for (int m = 0; m < 2; m++) {
        const int row = 2 * wave + m;
        gld_lds16((const bf16*)(mk + (size_t)(bt * 16 + row) * 8192 + gk * 1024 + gg4 * 4),
                  (bf16*)&Ml[0][row * 256]);
    }

    for (int sp = 0; sp < 32; ++sp) {
        const int nspf = (sp + 1 < 32) ? sp + 1 : 0;  // tail wraps (data unused)
        const int ni   = nspf * 32;
        const int nb   = (sp + 1) & 1, cb = sp & 1;

        // ---- 1. DMA slice sp+1 -> Ml[nb] (own rows; youngest vmem)
#pragma unroll
        for (int m = 0; m < 2; m++) {
            const int row = 2 * wave + m;
            gld_lds16((const bf16*)(mk + (size_t)(bt * 16 + row) * 8192 + gk * 1024 + ni + gg4 * 4),
                      (bf16*)&Ml[nb][row * 256]);
        }
        __builtin_amdgcn_sched_barrier(0);

        // ---- 2. wait: only DMA(sp+1) outstanding -> wk(sp)+DMA(sp) landed
        asm volatile("s_waitcnt vmcnt(2)" ::: "memory");
        __builtin_amdgcn_sched_barrier(0);

        // ---- 3. U-gen from wk(sp) -> Ul
#pragma unroll
        for (int hh = 0; hh < 2; hh++) {
            const int h = h0 + hh;
#pragma unroll
            for (int mt = 0; mt < 2; mt++) {
                f32x4 c4;
                c4[0] = 0.f; c4[1] = 0.f; c4[2] = 0.f; c4[3] = 0.f;
                c4 = __builtin_amdgcn_mfma_f32_16x16x32_bf16(wk[hh][mt][0], qf[hh][0], c4, 0, 0, 0);
                c4 = __builtin_amdgcn_mfma_f32_16x16x32_bf16(wk[hh][mt][1], qf[hh][1], c4, 0, 0, 0);
                bf16x4 o;
                o[0] = (bf16)c4[0]; o[1] = (bf16)c4[1]; o[2] = (bf16)c4[2]; o[3] = (bf16)c4[3];
                *(bf16x4*)((char*)Ul + ((((lm * 16 + h) * 32 + mt * 16 + q * 4) * 2)
                                        ^ (((lm ^ h) & 7) << 4))) = o;
            }
        }
        __builtin_amdgcn_sched_barrier(0);

        // ---- 4. issue wk(sp+1) into the SAME regs (WAR after U-gen)
#pragma unroll
        for (int hh = 0; hh < 2; hh++)
#pragma unroll
            for (int mt = 0; mt < 2; mt++)
#pragma unroll
                for (int half = 0; half < 2; half++)
                    wk[hh][mt][half] = *(const bf16x8*)(Wkf +
                        (size_t)(((nspf * 2 + mt) * 16 + h0 + hh) * 2 + half) * 512 + lane * 8);
        __builtin_amdgcn_sched_barrier(0);

        block_barrier();   // Ul visible (lgkm only; vmem stays in flight)

        // ---- 5. score accumulate from Ml[cb] (own rows)
#pragma unroll
        for (int lb = 0; lb < 2; lb++) {
            const int bb = wave * 2 + lb;
            const bf16x8 ua = *(const bf16x8*)((char*)Ul +
                ((((bb * 16 + lm) * 32 + q * 8) * 2) ^ (((bb ^ lm) & 7) << 4)));
            const int kk = lm & 7;
            const f32x4 a0 = *(const f32x4*)&Ml[cb][bb * 256 + (q * 2) * 32 + kk * 4];
            const f32x4 a1 = *(const f32x4*)&Ml[cb][bb * 256 + (q * 2 + 1) * 32 + kk * 4];
            bf16x8 mb;
            mb[0] = (bf16)a0[0]; mb[1] = (bf16)a0[1]; mb[2] = (bf16)a0[2]; mb[3] = (bf16)a0[3];
            mb[4] = (bf16)a1[0]; mb[5] = (bf16)a1[1]; mb[6] = (bf16)a1[2]; mb[7] = (bf16)a1[3];
            sacc[lb] = __builtin_amdgcn_mfma_f32_16x16x32_bf16(ua, mb, sacc[lb], 0, 0, 0);
        }
        block_barrier();   // Ul + Ml[cb] consumed
    }

    // ---- softmax over k (cols duplicated across lm and lm+8) + store attn
#pragma unroll
    for (int lb = 0; lb < 2; lb++) {
        const size_t bb = (size_t)(bt * 16 + wave * 2 + lb);
#pragma unroll
        for (int r = 0; r < 4; r++) {
            float s = sacc[lb][r] * 0.125f;          // DH^-0.5
            float mx = s;
            mx = fmaxf(mx, __shfl_xor(mx, 1));
            mx = fmaxf(mx, __shfl_xor(mx, 2));
            mx = fmaxf(mx, __shfl_xor(mx, 4));
            mx = fmaxf(mx, __shfl_xor(mx, 8));
            const float e = __expf(s - mx);
            float d = e;
            d += __shfl_xor(d, 1);
            d += __shfl_xor(d, 2);
            d += __shfl_xor(d, 4);
            d += __shfl_xor(d, 8);                   // = 2 * true denom
            const float a = e * (2.f / d);
            if (lm < 8) attn[bb * 128 + (q * 4 + r) * 8 + lm] = a;
        }
    }
}

// ---------------------------------------------------------------------------
// Fused apply kernel v12 (verified R18): register-neutral wb latency cover.
// ---------------------------------------------------------------------------
__global__ __launch_bounds__(512, 4)
void apply_attn(const float* __restrict__ attn, const float* __restrict__ mv,
                const bf16* __restrict__ Wvf, bf16* __restrict__ OH)
{
    __shared__ float Vl32[3][4096];    // 3x16KB [16 rows][8 k][32 i] fp32, LINEAR
    __shared__ bf16  Wl[16 * 16 * 32]; // 16KB [b][h][32 i] swz ^(((b^h)&7)<<4)

    const int tid  = threadIdx.x;
    const int wave = tid >> 6, lane = tid & 63;
    const int lm = lane & 15, q = lane >> 4;
    const int b0 = blockIdx.x * 16;
    const int h0 = wave * 2;

    const int gk = lane >> 3, gi4 = (lane & 7) * 4;

    bf16x8 afv[2][2];
#pragma unroll
    for (int lb = 0; lb < 2; lb++) {
        const float* ap = attn + (size_t)(b0 + wave * 2 + lb) * 128 + lm * 8;
        const float4 x = *(const float4*)(ap);
        const float4 y = *(const float4*)(ap + 4);
        bf16 a8[8];
        a8[0] = (bf16)x.x; a8[1] = (bf16)x.y; a8[2] = (bf16)x.z; a8[3] = (bf16)x.w;
        a8[4] = (bf16)y.x; a8[5] = (bf16)y.y; a8[6] = (bf16)y.z; a8[7] = (bf16)y.w;
#pragma unroll
        for (int mt = 0; mt < 2; mt++) {
            bf16x8 t;
#pragma unroll
            for (int j = 0; j < 8; j++) t[j] = (q == mt) ? a8[j] : (bf16)0.f;
            afv[lb][mt] = t;
        }
    }

    f32x4 oacc[2][4];
#pragma unroll
    for (int i = 0; i < 2; i++)
#pragma unroll
        for (int j = 0; j < 4; j++)
#pragma unroll
            for (int r = 0; r < 4; r++) oacc[i][j][r] = 0.f;

    // single wb register buffer (8 bf16x8 = 32 VGPR)
    bf16x8 wb[2][4];

    // ---- prologue: DMA(0), DMA(1), then wb(0) (queue: D0 < D1 < wb0)
#pragma unroll
    for (int m = 0; m < 2; m++) {
        const int row = 2 * wave + m;
        gld_lds16((const bf16*)(mv + (size_t)(b0 + row) * 8192 + gk * 1024 + gi4),
                  (bf16*)&Vl32[0][row * 256]);
    }
#pragma unroll
    for (int m = 0; m < 2; m++) {
        const int row = 2 * wave + m;
        gld_lds16((const bf16*)(mv + (size_t)(b0 + row) * 8192 + gk * 1024 + 32 + gi4),
                  (bf16*)&Vl32[1][row * 256]);
    }
#pragma unroll
    for (int hh = 0; hh < 2; hh++) {
        const int h = h0 + hh;
#pragma unroll
        for (int dt = 0; dt < 4; dt++)
            wb[hh][dt] = *(const bf16x8*)(Wvf +
                ((((size_t)h * 32 + 0) * 4 + dt) * 512 + lane * 8));
    }

    for (int sp = 0; sp < 32; ++sp) {
        const int ni = (sp + 2 < 32) ? sp * 32 + 64 : 0;   // tail wraps (unused)
        const int nwb = (sp + 1 < 32) ? sp + 1 : 0;        // tail wraps (unused)
        const int cb = sp % 3, nb = (sp + 2) % 3;

        // ---- 1. DMA slice sp+2 (youngest)
#pragma unroll
        for (int m = 0; m < 2; m++) {
            const int row = 2 * wave + m;
            gld_lds16((const bf16*)(mv + (size_t)(b0 + row) * 8192 + gk * 1024 + ni + gi4),
                      (bf16*)&Vl32[nb][row * 256]);
        }
        __builtin_amdgcn_sched_barrier(0);

        // ---- 2. wait own DMA(sp): younger = DMA(sp+1)2 + wb(sp)8 + DMA(sp+2)2
        asm volatile("s_waitcnt vmcnt(12)" ::: "memory");
        __builtin_amdgcn_sched_barrier(0);

        // ---- 3. Wm-gen from Vl32[cb] (own rows) -> Wl
#pragma unroll
        for (int lb = 0; lb < 2; lb++) {
            const int row = 2 * wave + lb;
            const int il = (q & 1) * 16 + lm;
            float v[8];
#pragma unroll
            for (int k = 0; k < 8; k++) v[k] = Vl32[cb][row * 256 + k * 32 + il];
            bf16x8 avf;
#pragma unroll
            for (int k = 0; k < 8; k++) avf[k] = (bf16)v[k];
#pragma unroll
            for (int mt = 0; mt < 2; mt++) {
                f32x4 c;
                c[0] = 0.f; c[1] = 0.f; c[2] = 0.f; c[3] = 0.f;
                c = __builtin_amdgcn_mfma_f32_16x16x32_bf16(avf, afv[lb][mt], c, 0, 0, 0);
                bf16x4 o;
                o[0] = (bf16)c[0]; o[1] = (bf16)c[1]; o[2] = (bf16)c[2]; o[3] = (bf16)c[3];
                *(bf16x4*)((char*)Wl + ((((row * 16 + lm) * 32 + mt * 16 + q * 4) * 2)
                                        ^ (((row ^ lm) & 7) << 4))) = o;
            }
        }
        block_barrier();   // Wl visible (lgkm only; vmem stays in flight)

        // ---- 4. wait wb(sp) (full superstep of cover): younger = DMA(sp+2)2
        asm volatile("s_waitcnt vmcnt(2)" ::: "memory");
        __builtin_amdgcn_sched_barrier(0);

        // ---- 5. OH: Wl reads + wb(sp) regs
#pragma unroll
        for (int hh = 0; hh < 2; hh++) {
            const int h = h0 + hh;
            const bf16x8 wa = *(const bf16x8*)((char*)Wl +
                ((((lm * 16 + h) * 32 + q * 8) * 2) ^ (((lm ^ h) & 7) << 4)));
#pragma unroll
            for (int dt = 0; dt < 4; dt++)
                oacc[hh][dt] = __builtin_amdgcn_mfma_f32_16x16x32_bf16(wa, wb[hh][dt], oacc[hh][dt], 0, 0, 0);
        }
        __builtin_amdgcn_sched_barrier(0);

        // ---- 6. issue wb(sp+1) into the SAME regs (WAR after OH)
#pragma unroll
        for (int hh = 0; hh < 2; hh++) {
            const int h = h0 + hh;
#pragma unroll
            for (int dt = 0; dt < 4; dt++)
                wb[hh][dt] = *(const bf16x8*)(Wvf +
                    ((((size_t)h * 32 + nwb) * 4 + dt) * 512 + lane * 8));
        }
        __builtin_amdgcn_sched_barrier(0);

        block_barrier();   // Wl consumed; safe to overwrite next superstep
    }

    // ---- store OH (rows b = q*4+r, cols h*64 + dt*16 + lm)
#pragma unroll
    for (int hh = 0; hh < 2; hh++) {
        const int h = h0 + hh;
#pragma unroll
        for (int dt = 0; dt < 4; dt++) {
#pragma unroll
            for (int r = 0; r < 4; r++)
                OH[(size_t)(b0 + q * 4 + r) * 1024 + h * 64 + dt * 16 + lm] = (bf16)oacc[hh][dt][r];
        }
    }
}

// ---------------------------------------------------------------------------
// sigmoid gate + residual + LayerNorm. One block per row.
// ---------------------------------------------------------------------------
__global__ __launch_bounds__(256)
void gate_ln_kernel(const float* __restrict__ hs, const float* __restrict__ mo,
                    const float* __restrict__ z,  const float* __restrict__ bg,
                    const float* __restrict__ lng, const float* __restrict__ lnb,
                    float* __restrict__ out)
{
    __shared__ float s1[4], s2[4];
    const int tid = threadIdx.x;
    const size_t base = (size_t)blockIdx.x * 1024 + tid * 4;

    const float4 h4 = *(const float4*)&hs[base];
    const float4 m4 = *(const float4*)&mo[base];
    const float4 z4 = *(const float4*)&z[base];
    const float4 bg4 = *(const float4*)&bg[tid * 4];

    float a[4];
    {
        const float g0 = 1.f / (1.f + __expf(-(z4.x + bg4.x)));
        const float g1 = 1.f / (1.f + __expf(-(z4.y + bg4.y)));
        const float g2 = 1.f / (1.f + __expf(-(z4.z + bg4.z)));
        const float g3 = 1.f / (1.f + __expf(-(z4.w + bg4.w)));
        a[0] = h4.x + g0 * m4.x;
        a[1] = h4.y + g1 * m4.y;
        a[2] = h4.z + g2 * m4.z;
        a[3] = h4.w + g3 * m4.w;
    }
    float sum = a[0] + a[1] + a[2] + a[3];
    float sq  = a[0]*a[0] + a[1]*a[1] + a[2]*a[2] + a[3]*a[3];
#pragma unroll
    for (int off = 32; off >= 1; off >>= 1) {
        sum += __shfl_xor(sum, off);
        sq  += __shfl_xor(sq,  off);
    }
    const int wave = tid >> 6;
    if ((tid & 63) == 0) { s1[wave] = sum; s2[wave] = sq; }
    __syncthreads();
    const float mean = (s1[0] + s1[1] + s1[2] + s1[3]) * (1.f / 1024.f);
    const float var  = (s2[0] + s2[1] + s2[2] + s2[3]) * (1.f / 1024.f) - mean * mean;
    const float inv  = rsqrtf(var + 1e-5f);

    const float4 g4 = *(const float4*)&lng[tid * 4];
    const float4 b4 = *(const float4*)&lnb[tid * 4];
    float4 o;
    o.x = (a[0] - mean) * inv * g4.x + b4.x;
    o.y = (a[1] - mean) * inv * g4.y + b4.y;
    o.z = (a[2] - mean) * inv * g4.z + b4.z;
    o.w = (a[3] - mean) * inv * g4.w + b4.w;
    *(float4*)&out[base] = o;
}

// ---------------------------------------------------------------------------
extern "C" void kernel_launch(void* const* d_in, const int* in_sizes, int n_in,
                              void* d_out, int out_size, void* d_ws, size_t ws_size,
                              hipStream_t stream)
{
    const float* hs  = (const float*)d_in[0];
    const float* mk  = (const float*)d_in[1];
    const float* mv  = (const float*)d_in[2];
    const float* Wq  = (const float*)d_in[3];
    const float* Wk  = (const float*)d_in[4];
    const float* Wv  = (const float*)d_in[5];
    const float* Wo  = (const float*)d_in[6];
    const float* Wg  = (const float*)d_in[7];
    const float* bg  = (const float*)d_in[8];
    const float* lng = (const float*)d_in[9];
    const float* lnb = (const float*)d_in[10];
    float* out = (float*)d_out;

    const int B = 8192;
    const dim3 tb(256);

    char* ws = (char*)d_ws;
    bf16*  Wq_t = (bf16*)(ws);                        // 2 MB  (1024x1024, N x K)
    bf16*  Wo_t = (bf16*)(ws + ((size_t)4  << 20));   // 2 MB
    bf16*  Wg_t = (bf16*)(ws + ((size_t)6  << 20));   // 4 MB  (1024x2048)
    bf16*  hs_b = (bf16*)(ws + ((size_t)12 << 20));   // 16 MB (8192x1024)
    bf16*  Qb   = (bf16*)(ws + ((size_t)28 << 20));   // 16 MB
    bf16*  OH   = (bf16*)(ws + ((size_t)44 << 20));   // 16 MB
    float* Mo   = (float*)(ws + ((size_t)60 << 20));  // 32 MB
    bf16*  Mo_b = (bf16*)(ws + ((size_t)92 << 20));   // 16 MB
    float* Zb   = (float*)(ws + ((size_t)108 << 20)); // 32 MB
    float* At   = (float*)(ws + ((size_t)140 << 20)); // 4 MB  (8192x16x8 fp32)
    bf16*  Wvf  = (bf16*)(ws + ((size_t)208 << 20));  // 2 MB  (fragment-major Wv)
    bf16*  Wkf  = (bf16*)(ws + ((size_t)210 << 20));  // 2 MB  (fragment-major Wk, 32-i)
    bf16*  Qf   = (bf16*)(ws + ((size_t)212 << 20));  // 16 MB (fragment-major Q)

    // one merged preprocessing launch (replaces 7)
    preprocess<<<dim3(9216), tb, 0, stream>>>(
        Wq, Wo, Wg, hs, Wv, Wk, Wq_t, Wo_t, Wg_t, hs_b, Wvf, Wkf);

    // Q = hs @ Wq -> bf16 (B x 1024)
    gemm_a97<false><<<dim3(8, 64, 1), tb, 0, stream>>>(
        hs_b, nullptr, Wq_t, nullptr, Qb,
        1024, 1024, 1024, 0, 1024, 1024, 0, 0, 0);
    // fragment-major Q for the score kernel
    repack_q<<<dim3(4096), tb, 0, stream>>>(Qb, Qf);
    // fused: U-gen + scores + softmax -> attn (B x 16 x 8 fp32)
    score_attn<<<dim3(B / 16), dim3(512), 0, stream>>>(Qf, Wkf, mk, At);
    // fused: W_mix-gen + V-proj -> OH (B x 1024 bf16)
    apply_attn<<<dim3(B / 16), dim3(512), 0, stream>>>(At, mv, Wvf, OH);
    // memory_out = OH @ Wo -> fp32 Mo + bf16 Mo_b
    gemm_a97<false><<<dim3(8, 64, 1), tb, 0, stream>>>(
        OH, nullptr, Wo_t, Mo, Mo_b,
        1024, 1024, 1024, 0, 1024, 1024, 0, 0, 0);
    // z = [hs, Mo] @ Wg -> fp32
    gemm_a97<true><<<dim3(8, 64, 1), tb, 0, stream>>>(
        hs_b, Mo_b, Wg_t, Zb, nullptr,
        2048, 1024, 1024, 1024, 2048, 1024, 0, 0, 0);
    // gate + residual + LayerNorm
    gate_ln_kernel<<<dim3(B), tb, 0, stream>>>(
        hs, Mo, Zb, bg, lng, lnb, out);
}

// Round 20
// 384.163 us; speedup vs baseline: 1.3701x; 1.0042x over previous
//
#include <hip/hip_runtime.h>
#include <hip/hip_bf16.h>

typedef __bf16 bf16;
typedef __bf16 bf16x8 __attribute__((ext_vector_type(8)));
typedef __bf16 bf16x4 __attribute__((ext_vector_type(4)));
typedef float  f32x4  __attribute__((ext_vector_type(4)));

// ---------------------------------------------------------------------------
// raw barrier: flush LDS ops (lgkmcnt), DO NOT drain vmcnt — in-flight global
// loads / global_load_lds survive the barrier.
// ---------------------------------------------------------------------------
__device__ __forceinline__ void block_barrier()
{
    asm volatile("s_waitcnt lgkmcnt(0)\n\ts_barrier" ::: "memory");
}

// ---------------------------------------------------------------------------
// async global->LDS 16B per lane: LDS dst = wave-uniform base + lane*16B
// ---------------------------------------------------------------------------
#if defined(__has_builtin)
#if __has_builtin(__builtin_amdgcn_global_load_lds)
#define HAS_GLD 1
#endif
#endif
#ifndef HAS_GLD
#define HAS_GLD 0
#endif

__device__ __forceinline__ void gld_lds16(const bf16* g, bf16* lds_base)
{
#if HAS_GLD
    __builtin_amdgcn_global_load_lds(
        (const __attribute__((address_space(1))) void*)g,
        (__attribute__((address_space(3))) void*)lds_base, 16, 0, 0);
#else
    *(bf16x8*)(lds_base + (threadIdx.x & 63) * 8) = *(const bf16x8*)g;
#endif
}

// ---------------------------------------------------------------------------
// Merged preprocessing kernel (verified R19).
// ---------------------------------------------------------------------------
__global__ __launch_bounds__(256)
void preprocess(const float* __restrict__ Wq, const float* __restrict__ Wo,
                const float* __restrict__ Wg, const float* __restrict__ hs,
                const float* __restrict__ Wv, const float* __restrict__ Wk,
                bf16* __restrict__ Wq_t, bf16* __restrict__ Wo_t,
                bf16* __restrict__ Wg_t, bf16* __restrict__ hs_b,
                bf16* __restrict__ Wvf,  bf16* __restrict__ Wkf)
{
    const int b = blockIdx.x, tid = threadIdx.x;

    if (b < 4096) {
        __shared__ float t[32][33];
        const float* src; bf16* dst; int bx, by, K, N;
        if (b < 1024)      { src = Wq; dst = Wq_t; const int l = b;        bx = l & 31; by = l >> 5; K = 1024; N = 1024; }
        else if (b < 2048) { src = Wo; dst = Wo_t; const int l = b - 1024; bx = l & 31; by = l >> 5; K = 1024; N = 1024; }
        else               { src = Wg; dst = Wg_t; const int l = b - 2048; bx = l & 31; by = l >> 5; K = 2048; N = 1024; }
        const int c = tid & 31, r0 = tid >> 5;
#pragma unroll
        for (int p = 0; p < 4; p++) {
            const int r = r0 + p * 8;
            t[r][c] = src[(size_t)(by * 32 + r) * N + bx * 32 + c];
        }
        __syncthreads();
#pragma unroll
        for (int p = 0; p < 4; p++) {
            const int r = r0 + p * 8;
            dst[(size_t)(bx * 32 + r) * K + by * 32 + c] = (bf16)t[c][r];
        }
    } else if (b < 8192) {
        const int i = (b - 4096) * 256 + tid;
        const float4* s = (const float4*)(hs + (size_t)i * 8);
        const float4 a = s[0], d = s[1];
        bf16x8 o;
        o[0] = (bf16)a.x; o[1] = (bf16)a.y; o[2] = (bf16)a.z; o[3] = (bf16)a.w;
        o[4] = (bf16)d.x; o[5] = (bf16)d.y; o[6] = (bf16)d.z; o[7] = (bf16)d.w;
        *(bf16x8*)(hs_b + (size_t)i * 8) = o;
    } else if (b < 8704) {
        const int t2 = (b - 8192) * 256 + tid;
        const int lane = t2 & 63, g = t2 >> 6;
        const int dt = g & 3, sp = (g >> 2) & 31, h = g >> 7;
        const int lm = lane & 15, q = lane >> 4;
        bf16x8 o;
#pragma unroll
        for (int j = 0; j < 8; j++)
            o[j] = (bf16)Wv[(size_t)(sp * 32 + q * 8 + j) * 1024 + h * 64 + dt * 16 + lm];
        *(bf16x8*)(Wvf + (size_t)g * 512 + lane * 8) = o;
    } else {
        const int t2 = (b - 8704) * 256 + tid;
        const int lane = t2 & 63, g = t2 >> 6;
        const int half = g & 1, h = (g >> 1) & 15, mt = (g >> 5) & 1, spw = g >> 6;
        const int lm = lane & 15, q = lane >> 4;
        const float* s = Wk + (size_t)(spw * 32 + mt * 16 + lm) * 1024
                            + h * 64 + half * 32 + q * 8;
        const f32x4 a = *(const f32x4*)s;
        const f32x4 d = *(const f32x4*)(s + 4);
        bf16x8 o;
        o[0] = (bf16)a[0]; o[1] = (bf16)a[1]; o[2] = (bf16)a[2]; o[3] = (bf16)a[3];
        o[4] = (bf16)d[0]; o[5] = (bf16)d[1]; o[6] = (bf16)d[2]; o[7] = (bf16)d[3];
        *(bf16x8*)(Wkf + (size_t)g * 512 + lane * 8) = o;
    }
}

// ---------------------------------------------------------------------------
// m97-style GEMM: C = A @ B.  A bf16 (rows via ldA), Bt bf16 (N x K, ldB).
// 128x128 tile, BK=32, global_load_lds staging, XCD swizzle (gridDim.x==8).
// Optional A2 for concat-K (gate).  Optional Cq: fragment-major Q output
// (replaces repack_q; epilogue-only index remap, K-loop untouched).
// ---------------------------------------------------------------------------
template<bool TWOA>
__global__ __launch_bounds__(256)
void gemm_a97(const bf16* __restrict__ A1, const bf16* __restrict__ A2,
              const bf16* __restrict__ Bt, float* __restrict__ Cf,
              bf16* __restrict__ Cb, bf16* __restrict__ Cq,
              int Kloop, int Ksplit,
              int ldA, int ldA2, int ldB, int ldC,
              long az, long bz, long cz)
{
    __shared__ bf16 Al[128 * 32];
    __shared__ bf16 Bl[128 * 32];

    const int z = blockIdx.z;
    A1 += (size_t)z * az;
    Bt += (size_t)z * bz;
    if (Cf) Cf += (size_t)z * cz;
    if (Cb) Cb += (size_t)z * cz;

    int bx, by;
    {
        const int gy = gridDim.y;
        const int flat = blockIdx.y * gridDim.x + blockIdx.x;
        if ((gy & 7) == 0 && gridDim.x == 8) {
            const int xcd = flat & 7, slot = flat >> 3, mpx = gy >> 3;
            by = xcd * mpx + (slot >> 3);
            bx = slot & 7;
        } else { bx = blockIdx.x; by = blockIdx.y; }
    }

    const int tid = threadIdx.x;
    const int wave = tid >> 6, lane = tid & 63;
    const int m0 = by * 128, n0 = bx * 128;
    const int rl = lane >> 2;
    const int kc = (lane & 3) * 8;
    const int wm = wave >> 1, wn = wave & 1, lm = lane & 15, quad = lane >> 4;

    f32x4 acc[4][4];
#pragma unroll
    for (int i = 0; i < 4; i++)
#pragma unroll
        for (int j = 0; j < 4; j++)
#pragma unroll
            for (int r = 0; r < 4; r++) acc[i][j][r] = 0.f;

    for (int k0 = 0; k0 < Kloop; k0 += 32) {
        const bf16* Ab; int kof, ld;
        if (TWOA && k0 >= Ksplit) { Ab = A2; kof = k0 - Ksplit; ld = ldA2; }
        else                      { Ab = A1; kof = k0;          ld = ldA;  }
        const int r0 = wave * 32 + rl, r1 = r0 + 16;
        gld_lds16(Ab + (size_t)(m0 + r0) * ld + kof + kc, Al + (wave * 32) * 32);
        gld_lds16(Ab + (size_t)(m0 + r1) * ld + kof + kc, Al + (wave * 32 + 16) * 32);
        gld_lds16(Bt + (size_t)(n0 + r0) * ldB + k0 + kc, Bl + (wave * 32) * 32);
        gld_lds16(Bt + (size_t)(n0 + r1) * ldB + k0 + kc, Bl + (wave * 32 + 16) * 32);
        __syncthreads();

        bf16x8 af[4], bfr[4];
#pragma unroll
        for (int i = 0; i < 4; i++)
            af[i] = *(const bf16x8*)&Al[(wm * 64 + i * 16 + lm) * 32 + quad * 8];
#pragma unroll
        for (int j = 0; j < 4; j++)
            bfr[j] = *(const bf16x8*)&Bl[(wn * 64 + j * 16 + lm) * 32 + quad * 8];
#pragma unroll
        for (int i = 0; i < 4; i++)
#pragma unroll
            for (int j = 0; j < 4; j++)
                acc[i][j] = __builtin_amdgcn_mfma_f32_16x16x32_bf16(af[i], bfr[j], acc[i][j], 0, 0, 0);
        __syncthreads();
    }

#pragma unroll
    for (int i = 0; i < 4; i++) {
        const int rbase = m0 + wm * 64 + i * 16 + quad * 4;
#pragma unroll
        for (int j = 0; j < 4; j++) {
            const int c = n0 + wn * 64 + j * 16 + lm;
#pragma unroll
            for (int r = 0; r < 4; r++) {
                const float v = acc[i][j][r];
                if (Cq) {
                    // fragment-major Q store (composed repack_q algebra):
                    // row=rbase+r, col=c ->
                    // Qf[(bt*32 + h*2 + half)*512 + q2*128 + lm2*8 + jj]
                    const int row = rbase + r;
                    const int bt2 = row >> 4, lm2 = row & 15;
                    const int hq = c >> 6, rem = c & 63;
                    const int half = rem >> 5, q2 = (rem & 31) >> 3, jj = rem & 7;
                    Cq[(size_t)(bt2 * 32 + hq * 2 + half) * 512 + q2 * 128 + lm2 * 8 + jj] = (bf16)v;
                } else {
                    const size_t idx = (size_t)(rbase + r) * ldC + c;
                    if (Cf) Cf[idx] = v;
                    if (Cb) Cb[idx] = (bf16)v;
                }
            }
        }
    }
}

// ---------------------------------------------------------------------------
// Fused score kernel v5 (verified R16/R18): register-neutral wk latency cover.
// ---------------------------------------------------------------------------
__global__ __launch_bounds__(512, 4)
void score_attn(const bf16* __restrict__ Qf, const bf16* __restrict__ Wkf,
                const float* __restrict__ mk, float* __restrict__ attn)
{
    __shared__ bf16  Ul[16 * 16 * 32]; // 16KB [b][h][32i] swz ^(((b^h)&7)<<4)
    __shared__ float Ml[2][4096];      // 2x16KB [16b][8 g4][8 k][4 i]

    const int tid  = threadIdx.x;
    const int wave = tid >> 6, lane = tid & 63;
    const int lm = lane & 15, q = lane >> 4;
    const int bt = blockIdx.x;         // rows [bt*16, bt*16+16)
    const int h0 = wave * 2;

    const int gk = lane & 7, gg4 = lane >> 3;

    // ---- persistent Q B-frags (coalesced 1KB bursts, loaded once)
    bf16x8 qf[2][2];
#pragma unroll
    for (int hh = 0; hh < 2; hh++)
#pragma unroll
        for (int half = 0; half < 2; half++)
            qf[hh][half] = *(const bf16x8*)(Qf +
                (size_t)((bt * 16 + h0 + hh) * 2 + half) * 512 + lane * 8);

    f32x4 sacc[2];
#pragma unroll
    for (int lb = 0; lb < 2; lb++)
#pragma unroll
        for (int r = 0; r < 4; r++) sacc[lb][r] = 0.f;

    // single wk register buffer (8 bf16x8 = 32 VGPR)
    bf16x8 wk[2][2][2];

    // ---- prologue: wk(0) (8 bursts), DMA(0) -> Ml[0]
#pragma unroll
    for (int hh = 0; hh < 2; hh++)
#pragma unroll
        for (int mt = 0; mt < 2; mt++)
#pragma unroll
            for (int half = 0; half < 2; half++)
                wk[hh][mt][half] = *(const bf16x8*)(Wkf +
                    (size_t)(((0 * 2 + mt) * 16 + h0 + hh) * 2 + half) * 512 + lane * 8);
#pragma unroll
    for (int m = 0; m < 2; m++) {
        const int row = 2 * wave + m;
        gld_lds16((const bf16*)(mk + (size_t)(bt * 16 + row) * 8192 + gk * 1024 + gg4 * 4),
                  (bf16*)&Ml[0][row * 256]);
    }

    for (int sp = 0; sp < 32; ++sp) {
        const int nspf = (sp + 1 < 32) ? sp + 1 : 0;  // tail wraps (data unused)
        const int ni   = nspf * 32;
        const int nb   = (sp + 1) & 1, cb = sp & 1;

        // ---- 1. DMA slice sp+1 -> Ml[nb] (own rows; youngest vmem)
#pragma unroll
        for (int m = 0; m < 2; m++) {
            const int row = 2 * wave + m;
            gld_lds16((const bf16*)(mk + (size_t)(bt * 16 + row) * 8192 + gk * 1024 + ni + gg4 * 4),
                      (bf16*)&Ml[nb][row * 256]);
        }
        __builtin_amdgcn_sched_barrier(0);

        // ---- 2. wait: only DMA(sp+1) outstanding -> wk(sp)+DMA(sp) landed
        asm volatile("s_waitcnt vmcnt(2)" ::: "memory");
        __builtin_amdgcn_sched_barrier(0);

        // ---- 3. U-gen from wk(sp) -> Ul
#pragma unroll
        for (int hh = 0; hh < 2; hh++) {
            const int h = h0 + hh;
#pragma unroll
            for (int mt = 0; mt < 2; mt++) {
                f32x4 c4;
                c4[0] = 0.f; c4[1] = 0.f; c4[2] = 0.f; c4[3] = 0.f;
                c4 = __builtin_amdgcn_mfma_f32_16x16x32_bf16(wk[hh][mt][0], qf[hh][0], c4, 0, 0, 0);
                c4 = __builtin_amdgcn_mfma_f32_16x16x32_bf16(wk[hh][mt][1], qf[hh][1], c4, 0, 0, 0);
                bf16x4 o;
                o[0] = (bf16)c4[0]; o[1] = (bf16)c4[1]; o[2] = (bf16)c4[2]; o[3] = (bf16)c4[3];
                *(bf16x4*)((char*)Ul + ((((lm * 16 + h) * 32 + mt * 16 + q * 4) * 2)
                                        ^ (((lm ^ h) & 7) << 4))) = o;
            }
        }
        __builtin_amdgcn_sched_barrier(0);

        // ---- 4. issue wk(sp+1) into the SAME regs (WAR after U-gen)
#pragma unroll
        for (int hh = 0; hh < 2; hh++)
#pragma unroll
            for (int mt = 0; mt < 2; mt++)
#pragma unroll
                for (int half = 0; half < 2; half++)
                    wk[hh][mt][half] = *(const bf16x8*)(Wkf +
                        (size_t)(((nspf * 2 + mt) * 16 + h0 + hh) * 2 + half) * 512 + lane * 8);
        __builtin_amdgcn_sched_barrier(0);

        block_barrier();   // Ul visible (lgkm only; vmem stays in flight)

        // ---- 5. score accumulate from Ml[cb] (own rows)
#pragma unroll
        for (int lb = 0; lb < 2; lb++) {
            const int bb = wave * 2 + lb;
            const bf16x8 ua = *(const bf16x8*)((char*)Ul +
                ((((bb * 16 + lm) * 32 + q * 8) * 2) ^ (((bb ^ lm) & 7) << 4)));
            const int kk = lm & 7;
            const f32x4 a0 = *(const f32x4*)&Ml[cb][bb * 256 + (q * 2) * 32 + kk * 4];
            const f32x4 a1 = *(const f32x4*)&Ml[cb][bb * 256 + (q * 2 + 1) * 32 + kk * 4];
            bf16x8 mb;
            mb[0] = (bf16)a0[0]; mb[1] = (bf16)a0[1]; mb[2] = (bf16)a0[2]; mb[3] = (bf16)a0[3];
            mb[4] = (bf16)a1[0]; mb[5] = (bf16)a1[1]; mb[6] = (bf16)a1[2]; mb[7] = (bf16)a1[3];
            sacc[lb] = __builtin_amdgcn_mfma_f32_16x16x32_bf16(ua, mb, sacc[lb], 0, 0, 0);
        }
        block_barrier();   // Ul + Ml[cb] consumed
    }

    // ---- softmax over k (cols duplicated across lm and lm+8) + store attn
#pragma unroll
    for (int lb = 0; lb < 2; lb++) {
        const size_t bb = (size_t)(bt * 16 + wave * 2 + lb);
#pragma unroll
        for (int r = 0; r < 4; r++) {
            float s = sacc[lb][r] * 0.125f;          // DH^-0.5
            float mx = s;
            mx = fmaxf(mx, __shfl_xor(mx, 1));
            mx = fmaxf(mx, __shfl_xor(mx, 2));
            mx = fmaxf(mx, __shfl_xor(mx, 4));
            mx = fmaxf(mx, __shfl_xor(mx, 8));
            const float e = __expf(s - mx);
            float d = e;
            d += __shfl_xor(d, 1);
            d += __shfl_xor(d, 2);
            d += __shfl_xor(d, 4);
            d += __shfl_xor(d, 8);                   // = 2 * true denom
            const float a = e * (2.f / d);
            if (lm < 8) attn[bb * 128 + (q * 4 + r) * 8 + lm] = a;
        }
    }
}

// ---------------------------------------------------------------------------
// Fused apply kernel v12 (verified R18): register-neutral wb latency cover.
// ---------------------------------------------------------------------------
__global__ __launch_bounds__(512, 4)
void apply_attn(const float* __restrict__ attn, const float* __restrict__ mv,
                const bf16* __restrict__ Wvf, bf16* __restrict__ OH)
{
    __shared__ float Vl32[3][4096];    // 3x16KB [16 rows][8 k][32 i] fp32, LINEAR
    __shared__ bf16  Wl[16 * 16 * 32]; // 16KB [b][h][32 i] swz ^(((b^h)&7)<<4)

    const int tid  = threadIdx.x;
    const int wave = tid >> 6, lane = tid & 63;
    const int lm = lane & 15, q = lane >> 4;
    const int b0 = blockIdx.x * 16;
    const int h0 = wave * 2;

    const int gk = lane >> 3, gi4 = (lane & 7) * 4;

    bf16x8 afv[2][2];
#pragma unroll
    for (int lb = 0; lb < 2; lb++) {
        const float* ap = attn + (size_t)(b0 + wave * 2 + lb) * 128 + lm * 8;
        const float4 x = *(const float4*)(ap);
        const float4 y = *(const float4*)(ap + 4);
        bf16 a8[8];
        a8[0] = (bf16)x.x; a8[1] = (bf16)x.y; a8[2] = (bf16)x.z; a8[3] = (bf16)x.w;
        a8[4] = (bf16)y.x; a8[5] = (bf16)y.y; a8[6] = (bf16)y.z; a8[7] = (bf16)y.w;
#pragma unroll
        for (int mt = 0; mt < 2; mt++) {
            bf16x8 t;
#pragma unroll
            for (int j = 0; j < 8; j++) t[j] = (q == mt) ? a8[j] : (bf16)0.f;
            afv[lb][mt] = t;
        }
    }

    f32x4 oacc[2][4];
#pragma unroll
    for (int i = 0; i < 2; i++)
#pragma unroll
        for (int j = 0; j < 4; j++)
#pragma unroll
            for (int r = 0; r < 4; r++) oacc[i][j][r] = 0.f;

    // single wb register buffer (8 bf16x8 = 32 VGPR)
    bf16x8 wb[2][4];

    // ---- prologue: DMA(0), DMA(1), then wb(0) (queue: D0 < D1 < wb0)
#pragma unroll
    for (int m = 0; m < 2; m++) {
        const int row = 2 * wave + m;
        gld_lds16((const bf16*)(mv + (size_t)(b0 + row) * 8192 + gk * 1024 + gi4),
                  (bf16*)&Vl32[0][row * 256]);
    }
#pragma unroll
    for (int m = 0; m < 2; m++) {
        const int row = 2 * wave + m;
        gld_lds16((const bf16*)(mv + (size_t)(b0 + row) * 8192 + gk * 1024 + 32 + gi4),
                  (bf16*)&Vl32[1][row * 256]);
    }
#pragma unroll
    for (int hh = 0; hh < 2; hh++) {
        const int h = h0 + hh;
#pragma unroll
        for (int dt = 0; dt < 4; dt++)
            wb[hh][dt] = *(const bf16x8*)(Wvf +
                ((((size_t)h * 32 + 0) * 4 + dt) * 512 + lane * 8));
    }

    for (int sp = 0; sp < 32; ++sp) {
        const int ni = (sp + 2 < 32) ? sp * 32 + 64 : 0;   // tail wraps (unused)
        const int nwb = (sp + 1 < 32) ? sp + 1 : 0;        // tail wraps (unused)
        const int cb = sp % 3, nb = (sp + 2) % 3;

        // ---- 1. DMA slice sp+2 (youngest)
#pragma unroll
        for (int m = 0; m < 2; m++) {
            const int row = 2 * wave + m;
            gld_lds16((const bf16*)(mv + (size_t)(b0 + row) * 8192 + gk * 1024 + ni + gi4),
                      (bf16*)&Vl32[nb][row * 256]);
        }
        __builtin_amdgcn_sched_barrier(0);

        // ---- 2. wait own DMA(sp): younger = DMA(sp+1)2 + wb(sp)8 + DMA(sp+2)2
        asm volatile("s_waitcnt vmcnt(12)" ::: "memory");
        __builtin_amdgcn_sched_barrier(0);

        // ---- 3. Wm-gen from Vl32[cb] (own rows) -> Wl
#pragma unroll
        for (int lb = 0; lb < 2; lb++) {
            const int row = 2 * wave + lb;
            const int il = (q & 1) * 16 + lm;
            float v[8];
#pragma unroll
            for (int k = 0; k < 8; k++) v[k] = Vl32[cb][row * 256 + k * 32 + il];
            bf16x8 avf;
#pragma unroll
            for (int k = 0; k < 8; k++) avf[k] = (bf16)v[k];
#pragma unroll
            for (int mt = 0; mt < 2; mt++) {
                f32x4 c;
                c[0] = 0.f; c[1] = 0.f; c[2] = 0.f; c[3] = 0.f;
                c = __builtin_amdgcn_mfma_f32_16x16x32_bf16(avf, afv[lb][mt], c, 0, 0, 0);
                bf16x4 o;
                o[0] = (bf16)c[0]; o[1] = (bf16)c[1]; o[2] = (bf16)c[2]; o[3] = (bf16)c[3];
                *(bf16x4*)((char*)Wl + ((((row * 16 + lm) * 32 + mt * 16 + q * 4) * 2)
                                        ^ (((row ^ lm) & 7) << 4))) = o;
            }
        }
        block_barrier();   // Wl visible (lgkm only; vmem stays in flight)

        // ---- 4. wait wb(sp) (full superstep of cover): younger = DMA(sp+2)2
        asm volatile("s_waitcnt vmcnt(2)" ::: "memory");
        __builtin_amdgcn_sched_barrier(0);

        // ---- 5. OH: Wl reads + wb(sp) regs
#pragma unroll
        for (int hh = 0; hh < 2; hh++) {
            const int h = h0 + hh;
            const bf16x8 wa = *(const bf16x8*)((char*)Wl +
                ((((lm * 16 + h) * 32 + q * 8) * 2) ^ (((lm ^ h) & 7) << 4)));
#pragma unroll
            for (int dt = 0; dt < 4; dt++)
                oacc[hh][dt] = __builtin_amdgcn_mfma_f32_16x16x32_bf16(wa, wb[hh][dt], oacc[hh][dt], 0, 0, 0);
        }
        __builtin_amdgcn_sched_barrier(0);

        // ---- 6. issue wb(sp+1) into the SAME regs (WAR after OH)
#pragma unroll
        for (int hh = 0; hh < 2; hh++) {
            const int h = h0 + hh;
#pragma unroll
            for (int dt = 0; dt < 4; dt++)
                wb[hh][dt] = *(const bf16x8*)(Wvf +
                    ((((size_t)h * 32 + nwb) * 4 + dt) * 512 + lane * 8));
        }
        __builtin_amdgcn_sched_barrier(0);

        block_barrier();   // Wl consumed; safe to overwrite next superstep
    }

    // ---- store OH (rows b = q*4+r, cols h*64 + dt*16 + lm)
#pragma unroll
    for (int hh = 0; hh < 2; hh++) {
        const int h = h0 + hh;
#pragma unroll
        for (int dt = 0; dt < 4; dt++) {
#pragma unroll
            for (int r = 0; r < 4; r++)
                OH[(size_t)(b0 + q * 4 + r) * 1024 + h * 64 + dt * 16 + lm] = (bf16)oacc[hh][dt][r];
        }
    }
}

// ---------------------------------------------------------------------------
// sigmoid gate + residual + LayerNorm. One block per row.
// ---------------------------------------------------------------------------
__global__ __launch_bounds__(256)
void gate_ln_kernel(const float* __restrict__ hs, const float* __restrict__ mo,
                    const float* __restrict__ z,  const float* __restrict__ bg,
                    const float* __restrict__ lng, const float* __restrict__ lnb,
                    float* __restrict__ out)
{
    __shared__ float s1[4], s2[4];
    const int tid = threadIdx.x;
    const size_t base = (size_t)blockIdx.x * 1024 + tid * 4;

    const float4 h4 = *(const float4*)&hs[base];
    const float4 m4 = *(const float4*)&mo[base];
    const float4 z4 = *(const float4*)&z[base];
    const float4 bg4 = *(const float4*)&bg[tid * 4];

    float a[4];
    {
        const float g0 = 1.f / (1.f + __expf(-(z4.x + bg4.x)));
        const float g1 = 1.f / (1.f + __expf(-(z4.y + bg4.y)));
        const float g2 = 1.f / (1.f + __expf(-(z4.z + bg4.z)));
        const float g3 = 1.f / (1.f + __expf(-(z4.w + bg4.w)));
        a[0] = h4.x + g0 * m4.x;
        a[1] = h4.y + g1 * m4.y;
        a[2] = h4.z + g2 * m4.z;
        a[3] = h4.w + g3 * m4.w;
    }
    float sum = a[0] + a[1] + a[2] + a[3];
    float sq  = a[0]*a[0] + a[1]*a[1] + a[2]*a[2] + a[3]*a[3];
#pragma unroll
    for (int off = 32; off >= 1; off >>= 1) {
        sum += __shfl_xor(sum, off);
        sq  += __shfl_xor(sq,  off);
    }
    const int wave = tid >> 6;
    if ((tid & 63) == 0) { s1[wave] = sum; s2[wave] = sq; }
    __syncthreads();
    const float mean = (s1[0] + s1[1] + s1[2] + s1[3]) * (1.f / 1024.f);
    const float var  = (s2[0] + s2[1] + s2[2] + s2[3]) * (1.f / 1024.f) - mean * mean;
    const float inv  = rsqrtf(var + 1e-5f);

    const float4 g4 = *(const float4*)&lng[tid * 4];
    const float4 b4 = *(const float4*)&lnb[tid * 4];
    float4 o;
    o.x = (a[0] - mean) * inv * g4.x + b4.x;
    o.y = (a[1] - mean) * inv * g4.y + b4.y;
    o.z = (a[2] - mean) * inv * g4.z + b4.z;
    o.w = (a[3] - mean) * inv * g4.w + b4.w;
    *(float4*)&out[base] = o;
}

// ---------------------------------------------------------------------------
extern "C" void kernel_launch(void* const* d_in, const int* in_sizes, int n_in,
                              void* d_out, int out_size, void* d_ws, size_t ws_size,
                              hipStream_t stream)
{
    const float* hs  = (const float*)d_in[0];
    const float* mk  = (const float*)d_in[1];
    const float* mv  = (const float*)d_in[2];
    const float* Wq  = (const float*)d_in[3];
    const float* Wk  = (const float*)d_in[4];
    const float* Wv  = (const float*)d_in[5];
    const float* Wo  = (const float*)d_in[6];
    const float* Wg  = (const float*)d_in[7];
    const float* bg  = (const float*)d_in[8];
    const float* lng = (const float*)d_in[9];
    const float* lnb = (const float*)d_in[10];
    float* out = (float*)d_out;

    const int B = 8192;
    const dim3 tb(256);

    char* ws = (char*)d_ws;
    bf16*  Wq_t = (bf16*)(ws);                        // 2 MB  (1024x1024, N x K)
    bf16*  Wo_t = (bf16*)(ws + ((size_t)4  << 20));   // 2 MB
    bf16*  Wg_t = (bf16*)(ws + ((size_t)6  << 20));   // 4 MB  (1024x2048)
    bf16*  hs_b = (bf16*)(ws + ((size_t)12 << 20));   // 16 MB (8192x1024)
    bf16*  OH   = (bf16*)(ws + ((size_t)44 << 20));   // 16 MB
    float* Mo   = (float*)(ws + ((size_t)60 << 20));  // 32 MB
    bf16*  Mo_b = (bf16*)(ws + ((size_t)92 << 20));   // 16 MB
    float* Zb   = (float*)(ws + ((size_t)108 << 20)); // 32 MB
    float* At   = (float*)(ws + ((size_t)140 << 20)); // 4 MB  (8192x16x8 fp32)
    bf16*  Wvf  = (bf16*)(ws + ((size_t)208 << 20));  // 2 MB  (fragment-major Wv)
    bf16*  Wkf  = (bf16*)(ws + ((size_t)210 << 20));  // 2 MB  (fragment-major Wk, 32-i)
    bf16*  Qf   = (bf16*)(ws + ((size_t)212 << 20));  // 16 MB (fragment-major Q)

    // one merged preprocessing launch
    preprocess<<<dim3(9216), tb, 0, stream>>>(
        Wq, Wo, Wg, hs, Wv, Wk, Wq_t, Wo_t, Wg_t, hs_b, Wvf, Wkf);

    // Q = hs @ Wq -> fragment-major Qf DIRECTLY (repack_q folded into epilogue)
    gemm_a97<false><<<dim3(8, 64, 1), tb, 0, stream>>>(
        hs_b, nullptr, Wq_t, nullptr, nullptr, Qf,
        1024, 1024, 1024, 0, 1024, 1024, 0, 0, 0);
    // fused: U-gen + scores + softmax -> attn (B x 16 x 8 fp32)
    score_attn<<<dim3(B / 16), dim3(512), 0, stream>>>(Qf, Wkf, mk, At);
    // fused: W_mix-gen + V-proj -> OH (B x 1024 bf16)
    apply_attn<<<dim3(B / 16), dim3(512), 0, stream>>>(At, mv, Wvf, OH);
    // memory_out = OH @ Wo -> fp32 Mo + bf16 Mo_b
    gemm_a97<false><<<dim3(8, 64, 1), tb, 0, stream>>>(
        OH, nullptr, Wo_t, Mo, Mo_b, nullptr,
        1024, 1024, 1024, 0, 1024, 1024, 0, 0, 0);
    // z = [hs, Mo] @ Wg -> fp32
    gemm_a97<true><<<dim3(8, 64, 1), tb, 0, stream>>>(
        hs_b, Mo_b, Wg_t, Zb, nullptr, nullptr,
        2048, 1024, 1024, 1024, 2048, 1024, 0, 0, 0);
    // gate + residual + LayerNorm
    gate_ln_kernel<<<dim3(B), tb, 0, stream>>>(
        hs, Mo, Zb, bg, lng, lnb, out);
}